// Round 7
// baseline (410.414 us; speedup 1.0000x reference)
//
#include <hip/hip_runtime.h>

// ESSAttn bf16-MFMA version. b=8, C=64, H=W=256 (N=65536), fp32 in/out.
// Math (exact refactor of reference):
//   out[b,n,d] = x_col(n)@wvln[d,:] + bias2[d] + w_row[n] * sum_c q2[n,c]*kvw[b][c][d]
//   kvw[c][d]  = inv_k[c] * sum_e kvu[c][e]*w_ln[d][e],  inv_k = 1/(256*max(sqrt(ksq_c),1e-12))
//   kvu[c][e]  = sum_n k2t[n,c]*v[n,e],  ksq_c = sum_n k2t^2
//   k2t = (k-mean_c(k))^2/(k2s+1e-7),  q2 = (q-mean)^2, w_row folds q2 normalizations.
// Round 7: all hot-path bf16 packing switched from manual bit-twiddle (~11 VALU ops per
// pair) to a single v_cvt_pk_bf16_f32 (RNE, bitwise-identical for finite inputs).
// Applied to k1/k3 staging, k1 ka/vb fragment packs, k3 qt writes. k0/k2 unchanged
// (cold path). Structure unchanged from round 6 (in-register kvu, DPP stats, 1 barrier).

typedef unsigned short u16;
typedef unsigned int u32;
typedef short bf16x8_t __attribute__((ext_vector_type(8)));
typedef short bf16x4_t __attribute__((ext_vector_type(4)));
typedef float f32x4_t __attribute__((ext_vector_type(4)));

#define NN 65536
#define G1 96
#define G3 192   // k3 persistent blocks per batch
#define STK 68   // bf16 qt LDS stride (elements)
#define SXB 68   // bf16 x-tile LDS stride (mult of 4 -> b64-aligned packed writes)

// cold-path scalar converter (k0 only)
static __device__ __forceinline__ u16 f2bf(float f) {
    union { float f; u32 u; } v; v.f = f;
    u32 r = v.u + 0x7FFFu + ((v.u >> 16) & 1u);
    return (u16)(r >> 16);
}
// hot-path pair converter: one VALU instruction, RNE (== f2bf bitwise for finite inputs)
static __device__ __forceinline__ u32 pack2(float a, float b) {
    u32 r;
    asm("v_cvt_pk_bf16_f32 %0, %1, %2" : "=v"(r) : "v"(a), "v"(b));
    return r;
}
static __device__ __forceinline__ bf16x4_t pack4(float a, float b, float c, float d) {
    uint2 t; t.x = pack2(a, b); t.y = pack2(c, d);
    return __builtin_bit_cast(bf16x4_t, t);
}

// 16-lane (row) sum reduction via DPP: bitwise-identical to xor-butterfly m=1,2,4,8.
template <int CTRL>
static __device__ __forceinline__ float dpp_addf(float x) {
    int y = __builtin_amdgcn_update_dpp(0, __float_as_int(x), CTRL, 0xF, 0xF, false);
    return x + __int_as_float(y);
}
static __device__ __forceinline__ float row_red16(float s) {
    s = dpp_addf<0xB1>(s);    // quad_perm [1,0,3,2]  == xor 1
    s = dpp_addf<0x4E>(s);    // quad_perm [2,3,0,1]  == xor 2
    s = dpp_addf<0x141>(s);   // row_half_mirror      == xor 4 (post quad-sum)
    s = dpp_addf<0x140>(s);   // row_mirror           == xor 8 (post half-sum)
    return s;
}

static __device__ __forceinline__ f32x4_t mfma_16x16x16(bf16x4_t a, bf16x4_t b, f32x4_t c) {
#if __has_builtin(__builtin_amdgcn_mfma_f32_16x16x16bf16_1k)
    return __builtin_amdgcn_mfma_f32_16x16x16bf16_1k(a, b, c, 0, 0, 0);
#else
    f32x4_t d;
    asm("v_mfma_f32_16x16x16_bf16 %0, %1, %2, %3" : "=v"(d) : "v"(a), "v"(b), "v"(c));
    return d;
#endif
}

// ---------------- K0: cast weights to bf16; wvln = w_ln @ w_v; bias2 = w_ln@b_v + b_ln
__global__ void k0_prep(const float* __restrict__ w_qkv, const float* __restrict__ b_qkv,
                        const float* __restrict__ w_ln, const float* __restrict__ b_ln,
                        u16* __restrict__ w_kv_bf, u16* __restrict__ w_q_bf,
                        u16* __restrict__ wvln_bf, float* __restrict__ bias2) {
    int idx = blockIdx.x * 256 + threadIdx.x;
    if (idx < 8192) {                       // rows 64..191 of w_qkv = [w_k | w_v]
        w_kv_bf[idx] = f2bf(w_qkv[4096 + idx]);
    } else if (idx < 12288) {               // rows 0..63 = w_q
        w_q_bf[idx - 8192] = f2bf(w_qkv[idx - 8192]);
    } else if (idx < 16384) {
        int i = idx - 12288; int d = i >> 6, c = i & 63;
        float s = 0.f;
        #pragma unroll 8
        for (int e = 0; e < 64; ++e)
            s += w_ln[d * 64 + e] * w_qkv[(128 + e) * 64 + c];
        wvln_bf[i] = f2bf(s);
    } else if (idx < 16448) {
        int d = idx - 16384;
        float s = b_ln[d];
        #pragma unroll 8
        for (int e = 0; e < 64; ++e)
            s += w_ln[d * 64 + e] * b_qkv[128 + e];
        bias2[d] = s;
    }
}

// ---------------- K1: per (g,b): loop n-tiles of 64; bf16 double-buffered x staging;
// MFMA k|v GEMM; DPP stats; in-register kvu via 16x16x16 MFMA (per-wave n-slice);
// cross-wave reduce + flush at end. One barrier per tile.
__global__ __launch_bounds__(256) void k1_kv(const float* __restrict__ x,
        const u16* __restrict__ w_kv_bf, const float* __restrict__ b_qkv,
        float* __restrict__ kvu_part, float* __restrict__ ksq_part) {
    __shared__ u16 xsb[2][64 * SXB];    // x tiles bf16: [c][n], double-buffered
    __shared__ float red[4][16][64];    // cross-wave kvu reduction (flush only)
    __shared__ float ksq_red[4][64];
    const int tid = threadIdx.x;
    const int w = tid >> 6, lane = tid & 63, q = lane >> 4, l15 = lane & 15;
    const int b = blockIdx.y, g = blockIdx.x;
    const float* xb = x + (size_t)b * 64 * NN;
    const int sc = tid >> 4;          // staging channel (+16*i)
    const int sn = (tid & 15) << 2;   // staging n offset (float4)
    const float* xg = xb + (size_t)sc * NN + sn;

    float bias[8];
    #pragma unroll
    for (int t8 = 0; t8 < 8; ++t8) bias[t8] = b_qkv[64 + 16 * t8 + l15];

    f32x4_t accK[4][4];   // kvu: [c-tile][e-tile], wave-local over its 16-n slices
    #pragma unroll
    for (int t4 = 0; t4 < 4; ++t4)
        #pragma unroll
        for (int et = 0; et < 4; ++et) accK[t4][et] = (f32x4_t){0.f, 0.f, 0.f, 0.f};
    float ksq_acc[4] = {0.f, 0.f, 0.f, 0.f};

    // prefetch first tile into registers
    float4 pf[4];
    #pragma unroll
    for (int i = 0; i < 4; ++i)
        pf[i] = *(const float4*)(xg + (size_t)(16 * i) * NN + g * 64);

    int p = 0;
    for (int t = g; t < NN / 64; t += G1) {
        // ---- commit prefetched tile to LDS as bf16 (1 cvt_pk per pair)
        u16* xp = xsb[p];
        #pragma unroll
        for (int i = 0; i < 4; ++i) {
            int c = 16 * i + sc;
            uint2 pk;
            pk.x = pack2(pf[i].x, pf[i].y);
            pk.y = pack2(pf[i].z, pf[i].w);
            *(uint2*)&xp[c * SXB + sn] = pk;
        }
        __syncthreads();   // single barrier per tile (xs double-buffered)
        // ---- issue next tile's loads; latency hides under compute below
        if (t + G1 < NN / 64) {
            #pragma unroll
            for (int i = 0; i < 4; ++i)
                pf[i] = *(const float4*)(xg + (size_t)(16 * i) * NN + (t + G1) * 64);
        }
        // ---- GEMM A: D[n][dcol], dcol 0..63 = k, 64..127 = v (K = 64 channels)
        f32x4_t accA[8];
        #pragma unroll
        for (int t8 = 0; t8 < 8; ++t8)
            accA[t8] = (f32x4_t){bias[t8], bias[t8], bias[t8], bias[t8]};
        #pragma unroll
        for (int ks = 0; ks < 2; ++ks) {
            union { u16 u[8]; bf16x8_t v; } af;   // x^T[n][c] frag, bf16 direct
            #pragma unroll
            for (int j = 0; j < 8; ++j)
                af.u[j] = xp[(ks * 32 + q * 8 + j) * SXB + 16 * w + l15];
            #pragma unroll
            for (int t8 = 0; t8 < 8; ++t8) {
                bf16x8_t bf = *(const bf16x8_t*)(w_kv_bf + (16 * t8 + l15) * 64 + ks * 32 + q * 8);
                accA[t8] = __builtin_amdgcn_mfma_f32_16x16x32_bf16(af.v, bf, accA[t8], 0, 0, 0);
            }
        }
        // ---- k stats per row (row = 4q + r): mean, 1/(k2s+eps) via DPP row reductions
        float mu[4], rin[4];
        #pragma unroll
        for (int r = 0; r < 4; ++r) {
            float a0 = accA[0][r], a1 = accA[1][r], a2 = accA[2][r], a3 = accA[3][r];
            float s1 = row_red16(a0 + a1 + a2 + a3);
            float s2 = row_red16(a0 * a0 + a1 * a1 + a2 * a2 + a3 * a3);
            mu[r] = s1 * 0.015625f;
            rin[r] = 1.f / (s2 - 64.f * mu[r] * mu[r] + 1e-7f);
        }
        // ---- k2t, v -> in-register bf16 fragments (accA layout == 16x16x16 operand layout)
        bf16x4_t ka[4], vb[4];
        #pragma unroll
        for (int t4 = 0; t4 < 4; ++t4) {
            float t2v[4];
            #pragma unroll
            for (int r = 0; r < 4; ++r) {
                float d = accA[t4][r] - mu[r];
                float t2 = d * d * rin[r];
                t2v[r] = t2;
                ksq_acc[t4] += t2 * t2;
            }
            ka[t4] = pack4(t2v[0], t2v[1], t2v[2], t2v[3]);
        }
        #pragma unroll
        for (int et = 0; et < 4; ++et)
            vb[et] = pack4(accA[4 + et][0], accA[4 + et][1], accA[4 + et][2], accA[4 + et][3]);
        // ---- kvu: D[c][e] += sum_{n in wave slice} k2t[n][c]*v[n][e], all in registers
        #pragma unroll
        for (int t4 = 0; t4 < 4; ++t4)
            #pragma unroll
            for (int et = 0; et < 4; ++et)
                accK[t4][et] = mfma_16x16x16(ka[t4], vb[et], accK[t4][et]);
        p ^= 1;
    }
    // ---- flush: cross-wave reduce kvu via LDS, then per-block partials to global
    float* kp = kvu_part + (size_t)(b * G1 + g) * 4096;
    #pragma unroll
    for (int t4 = 0; t4 < 4; ++t4) {
        __syncthreads();
        #pragma unroll
        for (int et = 0; et < 4; ++et)
            #pragma unroll
            for (int r = 0; r < 4; ++r)
                red[w][4 * q + r][16 * et + l15] = accK[t4][et][r];
        __syncthreads();
        #pragma unroll
        for (int l = 0; l < 4; ++l) {
            int idx = tid + 256 * l; int cl = idx >> 6, e = idx & 63;
            kp[(16 * t4 + cl) * 64 + e] =
                red[0][cl][e] + red[1][cl][e] + red[2][cl][e] + red[3][cl][e];
        }
    }
    #pragma unroll
    for (int t4 = 0; t4 < 4; ++t4) {
        float v = ksq_acc[t4];
        v += __shfl_xor(v, 16, 64);
        v += __shfl_xor(v, 32, 64);
        if (q == 0) ksq_red[w][16 * t4 + l15] = v;
    }
    __syncthreads();
    if (tid < 64)
        ksq_part[(size_t)(b * G1 + g) * 64 + tid] =
            ksq_red[0][tid] + ksq_red[1][tid] + ksq_red[2][tid] + ksq_red[3][tid];
}

// ---------------- K2: reduce partials over g; kvw_t[b][d][c] = bf16(inv_k[c]*sum_e kvu[c][e]*w_ln[d][e])
// (unchanged)
__global__ __launch_bounds__(256) void k2_kvw(const float* __restrict__ kvu_part,
        const float* __restrict__ ksq_part, const float* __restrict__ w_ln,
        u16* __restrict__ kvw_t) {
    __shared__ float wln_s[64 * 68];
    __shared__ float kvr[4 * 68];
    __shared__ float ksq_r[64];
    __shared__ float inv_k[4];
    const int tid = threadIdx.x;
    const int c0 = blockIdx.x * 4, b = blockIdx.y;
    #pragma unroll
    for (int lidx = 0; lidx < 16; ++lidx) {
        int idx = tid + 256 * lidx;
        wln_s[(idx >> 6) * 68 + (idx & 63)] = w_ln[idx];
    }
    {   // thread (cl = tid>>6, e = tid&63): sum kvu over g, 8 concurrent chains
        const int cl = tid >> 6, e = tid & 63;
        const float* p = kvu_part + (size_t)b * G1 * 4096 + (c0 + cl) * 64 + e;
        float s[8];
        #pragma unroll
        for (int k = 0; k < 8; ++k) s[k] = 0.f;
        for (int g = 0; g < G1; g += 8) {
            #pragma unroll
            for (int k = 0; k < 8; ++k) s[k] += p[(size_t)(g + k) * 4096];
        }
        kvr[cl * 68 + e] = ((s[0] + s[1]) + (s[2] + s[3])) + ((s[4] + s[5]) + (s[6] + s[7]));
    }
    if (tid < 64) {  // ksq reduce spread over 16 g-partials x 4 c
        const int cl = tid & 3, gp = tid >> 2;
        float s = 0.f;
        #pragma unroll
        for (int k = 0; k < 6; ++k)
            s += ksq_part[(size_t)(b * G1 + gp + 16 * k) * 64 + c0 + cl];
        ksq_r[tid] = s;
    }
    __syncthreads();
    if (tid < 4) {
        float s = 0.f;
        #pragma unroll
        for (int gp = 0; gp < 16; ++gp) s += ksq_r[gp * 4 + tid];
        inv_k[tid] = 1.f / (fmaxf(sqrtf(s), 1e-12f) * 256.f);
    }
    __syncthreads();
    {   // thread (d = tid>>2, cl = tid&3): 64-wide dot, vectorized
        const int d = tid >> 2, cl = tid & 3;
        float s = 0.f;
        #pragma unroll
        for (int e4 = 0; e4 < 16; ++e4) {
            float4 a  = *(const float4*)&kvr[cl * 68 + 4 * e4];
            float4 wv = *(const float4*)&wln_s[d * 68 + 4 * e4];
            s += a.x * wv.x + a.y * wv.y + a.z * wv.z + a.w * wv.w;
        }
        kvw_t[(size_t)b * 4096 + d * 64 + c0 + cl] = f2bf(s * inv_k[cl]);
    }
}

// ---------------- K3: persistent multi-tile; bf16 double-buffered staging; DPP stats;
// operand-swapped d-major o/t2 GEMMs; direct register->global stores. One barrier/tile
// (qt + wrow are same-wave-only: lgkmcnt dependency, no cross-wave hazard).
__global__ __launch_bounds__(256) void k3_out(const float* __restrict__ x,
        const u16* __restrict__ w_q_bf, const u16* __restrict__ wvln_bf,
        const float* __restrict__ b_qkv, const float* __restrict__ bias2,
        const u16* __restrict__ kvw_t, float* __restrict__ out) {
    __shared__ u16 xsb[2][64 * SXB];   // x tiles bf16: [c][n], double-buffered
    __shared__ u16 qt[64 * STK];       // q2: [n][c] bf16 (same-wave rows only)
    __shared__ float wrow_s[4][16];    // per-wave w_row redistribution
    const int tid = threadIdx.x;
    const int w = tid >> 6, lane = tid & 63, q = lane >> 4, l15 = lane & 15;
    const int b = blockIdx.y, g = blockIdx.x;
    const float* xb = x + (size_t)b * 64 * NN;
    const int sc = tid >> 4, sn = (tid & 15) << 2;
    const float* xg = xb + (size_t)sc * NN + sn;
    const u16* kvb = kvw_t + (size_t)b * 4096;

    float biasQ[4];
    #pragma unroll
    for (int t4 = 0; t4 < 4; ++t4) biasQ[t4] = b_qkv[16 * t4 + l15];
    float biasO[4][4];   // bias2[d] for d = 16*dt + 4*q + r (d-major accO init)
    #pragma unroll
    for (int dt = 0; dt < 4; ++dt)
        #pragma unroll
        for (int r = 0; r < 4; ++r) biasO[dt][r] = bias2[16 * dt + 4 * q + r];

    // prefetch first tile into registers
    float4 pf[4];
    #pragma unroll
    for (int i = 0; i < 4; ++i)
        pf[i] = *(const float4*)(xg + (size_t)(16 * i) * NN + g * 64);

    int p = 0;
    for (int t = g; t < NN / 64; t += G3) {
        const int n0 = t * 64;
        // ---- commit prefetched tile to LDS as bf16
        u16* xp = xsb[p];
        #pragma unroll
        for (int i = 0; i < 4; ++i) {
            int c = 16 * i + sc;
            uint2 pk;
            pk.x = pack2(pf[i].x, pf[i].y);
            pk.y = pack2(pf[i].z, pf[i].w);
            *(uint2*)&xp[c * SXB + sn] = pk;
        }
        __syncthreads();   // single barrier per tile
        if (t + G3 < NN / 64) {
            #pragma unroll
            for (int i = 0; i < 4; ++i)
                pf[i] = *(const float4*)(xg + (size_t)(16 * i) * NN + (t + G3) * 64);
        }
        // ---- GEMM A: accQ = q (n-major, for stats); accO = o = x@wvln^T + bias2 (d-major)
        f32x4_t accQ[4], accO[4];
        #pragma unroll
        for (int t4 = 0; t4 < 4; ++t4)
            accQ[t4] = (f32x4_t){biasQ[t4], biasQ[t4], biasQ[t4], biasQ[t4]};
        #pragma unroll
        for (int dt = 0; dt < 4; ++dt)
            accO[dt] = (f32x4_t){biasO[dt][0], biasO[dt][1], biasO[dt][2], biasO[dt][3]};
        #pragma unroll
        for (int ks = 0; ks < 2; ++ks) {
            union { u16 u[8]; bf16x8_t v; } af;   // x^T[n][c] frag, bf16 direct
            #pragma unroll
            for (int j = 0; j < 8; ++j)
                af.u[j] = xp[(ks * 32 + q * 8 + j) * SXB + 16 * w + l15];
            #pragma unroll
            for (int t4 = 0; t4 < 4; ++t4) {
                bf16x8_t bq = *(const bf16x8_t*)(w_q_bf + (16 * t4 + l15) * 64 + ks * 32 + q * 8);
                accQ[t4] = __builtin_amdgcn_mfma_f32_16x16x32_bf16(af.v, bq, accQ[t4], 0, 0, 0);
            }
            #pragma unroll
            for (int dt = 0; dt < 4; ++dt) {
                bf16x8_t aw = *(const bf16x8_t*)(wvln_bf + (16 * dt + l15) * 64 + ks * 32 + q * 8);
                accO[dt] = __builtin_amdgcn_mfma_f32_16x16x32_bf16(aw, af.v, accO[dt], 0, 0, 0);
            }
        }
        // ---- q stats via DPP: mu, q2s; q2; w_row = 1/max(||q2||, 1e-12*(q2s+eps))
        float mu[4], q2s[4];
        #pragma unroll
        for (int r = 0; r < 4; ++r) {
            float a0 = accQ[0][r], a1 = accQ[1][r], a2 = accQ[2][r], a3 = accQ[3][r];
            float s1 = row_red16(a0 + a1 + a2 + a3);
            float s2 = row_red16(a0 * a0 + a1 * a1 + a2 * a2 + a3 * a3);
            mu[r] = s1 * 0.015625f;
            q2s[r] = s2 - 64.f * mu[r] * mu[r];
        }
        float q2v[4][4];
        float s4[4] = {0.f, 0.f, 0.f, 0.f};
        #pragma unroll
        for (int t4 = 0; t4 < 4; ++t4)
            #pragma unroll
            for (int r = 0; r < 4; ++r) {
                float d = accQ[t4][r] - mu[r];
                float v2 = d * d;
                q2v[t4][r] = v2;
                s4[r] += v2 * v2;
            }
        float w_row[4];
        #pragma unroll
        for (int r = 0; r < 4; ++r) {
            float s = row_red16(s4[r]);
            w_row[r] = 1.f / fmaxf(sqrtf(s), 1e-12f * (q2s[r] + 1e-7f));
        }
        // ---- redistribute w_row: row n=16w+4q+r -> lane col l15 (same wave only)
        if (l15 == 0) {
            #pragma unroll
            for (int r = 0; r < 4; ++r) wrow_s[w][4 * q + r] = w_row[r];
        }
        // ---- q2 -> qt LDS ([n][c] bf16, same-wave rows): 2 cvt_pk + 2 shifts per t4
        #pragma unroll
        for (int t4 = 0; t4 < 4; ++t4) {
            u32 lo = pack2(q2v[t4][0], q2v[t4][1]);
            u32 hi = pack2(q2v[t4][2], q2v[t4][3]);
            u16* qp = &qt[(16 * w + 4 * q) * STK + 16 * t4 + l15];
            qp[0 * STK] = (u16)lo;
            qp[1 * STK] = (u16)(lo >> 16);
            qp[2 * STK] = (u16)hi;
            qp[3 * STK] = (u16)(hi >> 16);
        }
        // ---- GEMM B (d-major): t2[d][n] = sum_c kvw[d][c]-frag * q2[n][c]
        f32x4_t accB[4];
        #pragma unroll
        for (int dt = 0; dt < 4; ++dt) accB[dt] = (f32x4_t){0.f, 0.f, 0.f, 0.f};
        #pragma unroll
        for (int ks = 0; ks < 2; ++ks) {
            union { bf16x8_t v; uint2 h[2]; } b2;   // q2[n][c] frag as B-operand
            const u16* bp = &qt[(16 * w + l15) * STK + ks * 32 + q * 8];
            b2.h[0] = *(const uint2*)bp;
            b2.h[1] = *(const uint2*)(bp + 4);
            #pragma unroll
            for (int dt = 0; dt < 4; ++dt) {
                bf16x8_t ak = *(const bf16x8_t*)(kvb + (16 * dt + l15) * 64 + ks * 32 + q * 8);
                accB[dt] = __builtin_amdgcn_mfma_f32_16x16x32_bf16(ak, b2.v, accB[dt], 0, 0, 0);
            }
        }
        float wr = wrow_s[w][l15];
        // ---- epilogue: out[d][n] = o + w_row[n]*t2, direct register stores
        #pragma unroll
        for (int dt = 0; dt < 4; ++dt) {
            float* op = out + ((size_t)(b * 64 + 16 * dt + 4 * q)) * NN + n0 + 16 * w + l15;
            #pragma unroll
            for (int r = 0; r < 4; ++r)
                op[(size_t)r * NN] = accO[dt][r] + wr * accB[dt][r];
        }
        p ^= 1;
    }
}

extern "C" void kernel_launch(void* const* d_in, const int* in_sizes, int n_in,
                              void* d_out, int out_size, void* d_ws, size_t ws_size,
                              hipStream_t stream) {
    const float* x     = (const float*)d_in[0];
    const float* w_qkv = (const float*)d_in[1];
    const float* b_qkv = (const float*)d_in[2];
    const float* w_ln  = (const float*)d_in[3];
    const float* b_ln  = (const float*)d_in[4];
    float* out = (float*)d_out;
    char* ws = (char*)d_ws;
    // byte layout (total 12.88 MB, unchanged)
    float* kvu_part = (float*)(ws);                       // 8*96*4096 f32
    float* ksq_part = (float*)(ws + 12582912);            // 8*96*64 f32
    u16*   kvw_t    = (u16*)  (ws + 12779520);            // 8*4096 bf16
    u16*   w_kv_bf  = (u16*)  (ws + 12845056);            // 128*64 bf16
    u16*   w_q_bf   = (u16*)  (ws + 12861440);            // 64*64 bf16
    u16*   wvln_bf  = (u16*)  (ws + 12869632);            // 64*64 bf16
    float* bias2    = (float*)(ws + 12877824);            // 64 f32

    k0_prep<<<dim3(65), dim3(256), 0, stream>>>(w_qkv, b_qkv, w_ln, b_ln,
                                                w_kv_bf, w_q_bf, wvln_bf, bias2);
    k1_kv<<<dim3(G1, 8), dim3(256), 0, stream>>>(x, w_kv_bf, b_qkv, kvu_part, ksq_part);
    k2_kvw<<<dim3(16, 8), dim3(256), 0, stream>>>(kvu_part, ksq_part, w_ln, kvw_t);
    k3_out<<<dim3(G3, 8), dim3(256), 0, stream>>>(x, w_q_bf, wvln_bf, b_qkv, bias2, kvw_t, out);
}

// Round 8
// 379.873 us; speedup vs baseline: 1.0804x; 1.0804x over previous
//
#include <hip/hip_runtime.h>

// ESSAttn bf16-MFMA version. b=8, C=64, H=W=256 (N=65536), fp32 in/out.
// Math (exact refactor of reference):
//   out[b,n,d] = x_col(n)@wvln[d,:] + bias2[d] + w_row[n] * sum_c q2[n,c]*kvw[b][c][d]
//   kvw[c][d]  = inv_k[c] * sum_e kvu[c][e]*w_ln[d][e],  inv_k = 1/(256*max(sqrt(ksq_c),1e-12))
//   kvu[c][e]  = sum_n k2t[n,c]*v[n,e],  ksq_c = sum_n k2t^2
//   k2t = (k-mean_c(k))^2/(k2s+1e-7),  q2 = (q-mean)^2, w_row folds q2 normalizations.
// Round 8: REVERT round-7's inline-asm cvt_pk (regressed -36%, changed numerics; m240's
// warning confirmed) -> round-6 bit-twiddle pack. NEW: 2-deep register prefetch in k1/k3
// (named pfA/pfB, tile-pair loop so all indices static; refill issued before the barrier).
// Little's law: 1-deep kept ~12KB/CU in flight vs ~22KB needed at ~900ns HBM latency.

typedef unsigned short u16;
typedef unsigned int u32;
typedef short bf16x8_t __attribute__((ext_vector_type(8)));
typedef short bf16x4_t __attribute__((ext_vector_type(4)));
typedef float f32x4_t __attribute__((ext_vector_type(4)));

#define NN 65536
#define G1 96
#define G3 192   // k3 persistent blocks per batch
#define STK 68   // bf16 qt LDS stride (elements)
#define SXB 68   // bf16 x-tile LDS stride (mult of 4 -> b64-aligned packed writes)

static __device__ __forceinline__ u16 f2bf(float f) {
    union { float f; u32 u; } v; v.f = f;
    u32 r = v.u + 0x7FFFu + ((v.u >> 16) & 1u);
    return (u16)(r >> 16);
}
static __device__ __forceinline__ u32 pack2(float a, float b) {
    return (u32)f2bf(a) | ((u32)f2bf(b) << 16);
}
static __device__ __forceinline__ bf16x4_t pack4(float a, float b, float c, float d) {
    uint2 t; t.x = pack2(a, b); t.y = pack2(c, d);
    return __builtin_bit_cast(bf16x4_t, t);
}

// 16-lane (row) sum reduction via DPP: bitwise-identical to xor-butterfly m=1,2,4,8.
template <int CTRL>
static __device__ __forceinline__ float dpp_addf(float x) {
    int y = __builtin_amdgcn_update_dpp(0, __float_as_int(x), CTRL, 0xF, 0xF, false);
    return x + __int_as_float(y);
}
static __device__ __forceinline__ float row_red16(float s) {
    s = dpp_addf<0xB1>(s);    // quad_perm [1,0,3,2]  == xor 1
    s = dpp_addf<0x4E>(s);    // quad_perm [2,3,0,1]  == xor 2
    s = dpp_addf<0x141>(s);   // row_half_mirror      == xor 4 (post quad-sum)
    s = dpp_addf<0x140>(s);   // row_mirror           == xor 8 (post half-sum)
    return s;
}

static __device__ __forceinline__ f32x4_t mfma_16x16x16(bf16x4_t a, bf16x4_t b, f32x4_t c) {
#if __has_builtin(__builtin_amdgcn_mfma_f32_16x16x16bf16_1k)
    return __builtin_amdgcn_mfma_f32_16x16x16bf16_1k(a, b, c, 0, 0, 0);
#else
    f32x4_t d;
    asm("v_mfma_f32_16x16x16_bf16 %0, %1, %2, %3" : "=v"(d) : "v"(a), "v"(b), "v"(c));
    return d;
#endif
}

// ---------------- K0: cast weights to bf16; wvln = w_ln @ w_v; bias2 = w_ln@b_v + b_ln
__global__ void k0_prep(const float* __restrict__ w_qkv, const float* __restrict__ b_qkv,
                        const float* __restrict__ w_ln, const float* __restrict__ b_ln,
                        u16* __restrict__ w_kv_bf, u16* __restrict__ w_q_bf,
                        u16* __restrict__ wvln_bf, float* __restrict__ bias2) {
    int idx = blockIdx.x * 256 + threadIdx.x;
    if (idx < 8192) {                       // rows 64..191 of w_qkv = [w_k | w_v]
        w_kv_bf[idx] = f2bf(w_qkv[4096 + idx]);
    } else if (idx < 12288) {               // rows 0..63 = w_q
        w_q_bf[idx - 8192] = f2bf(w_qkv[idx - 8192]);
    } else if (idx < 16384) {
        int i = idx - 12288; int d = i >> 6, c = i & 63;
        float s = 0.f;
        #pragma unroll 8
        for (int e = 0; e < 64; ++e)
            s += w_ln[d * 64 + e] * w_qkv[(128 + e) * 64 + c];
        wvln_bf[i] = f2bf(s);
    } else if (idx < 16448) {
        int d = idx - 16384;
        float s = b_ln[d];
        #pragma unroll 8
        for (int e = 0; e < 64; ++e)
            s += w_ln[d * 64 + e] * b_qkv[128 + e];
        bias2[d] = s;
    }
}

// ---------------- K1: per (g,b): loop n-tiles of 64; bf16 double-buffered x staging with
// 2-deep register prefetch; MFMA k|v GEMM; DPP stats; in-register kvu via 16x16x16 MFMA;
// cross-wave reduce + flush at end. One barrier per tile.
__global__ __launch_bounds__(256) void k1_kv(const float* __restrict__ x,
        const u16* __restrict__ w_kv_bf, const float* __restrict__ b_qkv,
        float* __restrict__ kvu_part, float* __restrict__ ksq_part) {
    __shared__ u16 xsb[2][64 * SXB];    // x tiles bf16: [c][n], double-buffered
    __shared__ float red[4][16][64];    // cross-wave kvu reduction (flush only)
    __shared__ float ksq_red[4][64];
    const int tid = threadIdx.x;
    const int w = tid >> 6, lane = tid & 63, q = lane >> 4, l15 = lane & 15;
    const int b = blockIdx.y, g = blockIdx.x;
    const float* xb = x + (size_t)b * 64 * NN;
    const int sc = tid >> 4;          // staging channel (+16*i)
    const int sn = (tid & 15) << 2;   // staging n offset (float4)
    const float* xg = xb + (size_t)sc * NN + sn;

    float bias[8];
    #pragma unroll
    for (int t8 = 0; t8 < 8; ++t8) bias[t8] = b_qkv[64 + 16 * t8 + l15];

    f32x4_t accK[4][4];   // kvu: [c-tile][e-tile], wave-local over its 16-n slices
    #pragma unroll
    for (int t4 = 0; t4 < 4; ++t4)
        #pragma unroll
        for (int et = 0; et < 4; ++et) accK[t4][et] = (f32x4_t){0.f, 0.f, 0.f, 0.f};
    float ksq_acc[4] = {0.f, 0.f, 0.f, 0.f};

    // 2-deep prefetch: pfA = tile t, pfB = tile t+G1 (named buffers: static indexing)
    float4 pfA[4], pfB[4];
    #pragma unroll
    for (int i = 0; i < 4; ++i)
        pfA[i] = *(const float4*)(xg + (size_t)(16 * i) * NN + g * 64);
    if (g + G1 < NN / 64) {
        #pragma unroll
        for (int i = 0; i < 4; ++i)
            pfB[i] = *(const float4*)(xg + (size_t)(16 * i) * NN + (g + G1) * 64);
    }

    // one tile: commit pfb->xp, refill pfb from tile tnext (before barrier), compute on xp
    auto tile = [&](float4 (&pfb)[4], u16* __restrict__ xp, int tnext) {
        #pragma unroll
        for (int i = 0; i < 4; ++i) {
            int c = 16 * i + sc;
            uint2 pk;
            pk.x = pack2(pfb[i].x, pfb[i].y);
            pk.y = pack2(pfb[i].z, pfb[i].w);
            *(uint2*)&xp[c * SXB + sn] = pk;
        }
        if (tnext < NN / 64) {   // refill 2 tiles ahead; issued before the barrier
            #pragma unroll
            for (int i = 0; i < 4; ++i)
                pfb[i] = *(const float4*)(xg + (size_t)(16 * i) * NN + tnext * 64);
        }
        __syncthreads();   // single barrier per tile (xs double-buffered)
        // ---- GEMM A: D[n][dcol], dcol 0..63 = k, 64..127 = v (K = 64 channels)
        f32x4_t accA[8];
        #pragma unroll
        for (int t8 = 0; t8 < 8; ++t8)
            accA[t8] = (f32x4_t){bias[t8], bias[t8], bias[t8], bias[t8]};
        #pragma unroll
        for (int ks = 0; ks < 2; ++ks) {
            union { u16 u[8]; bf16x8_t v; } af;   // x^T[n][c] frag, bf16 direct
            #pragma unroll
            for (int j = 0; j < 8; ++j)
                af.u[j] = xp[(ks * 32 + q * 8 + j) * SXB + 16 * w + l15];
            #pragma unroll
            for (int t8 = 0; t8 < 8; ++t8) {
                bf16x8_t bf = *(const bf16x8_t*)(w_kv_bf + (16 * t8 + l15) * 64 + ks * 32 + q * 8);
                accA[t8] = __builtin_amdgcn_mfma_f32_16x16x32_bf16(af.v, bf, accA[t8], 0, 0, 0);
            }
        }
        // ---- k stats per row (row = 4q + r): mean, 1/(k2s+eps) via DPP row reductions
        float mu[4], rin[4];
        #pragma unroll
        for (int r = 0; r < 4; ++r) {
            float a0 = accA[0][r], a1 = accA[1][r], a2 = accA[2][r], a3 = accA[3][r];
            float s1 = row_red16(a0 + a1 + a2 + a3);
            float s2 = row_red16(a0 * a0 + a1 * a1 + a2 * a2 + a3 * a3);
            mu[r] = s1 * 0.015625f;
            rin[r] = 1.f / (s2 - 64.f * mu[r] * mu[r] + 1e-7f);
        }
        // ---- k2t, v -> in-register bf16 fragments (accA layout == 16x16x16 operand layout)
        bf16x4_t ka[4], vb[4];
        #pragma unroll
        for (int t4 = 0; t4 < 4; ++t4) {
            float t2v[4];
            #pragma unroll
            for (int r = 0; r < 4; ++r) {
                float d = accA[t4][r] - mu[r];
                float t2 = d * d * rin[r];
                t2v[r] = t2;
                ksq_acc[t4] += t2 * t2;
            }
            ka[t4] = pack4(t2v[0], t2v[1], t2v[2], t2v[3]);
        }
        #pragma unroll
        for (int et = 0; et < 4; ++et)
            vb[et] = pack4(accA[4 + et][0], accA[4 + et][1], accA[4 + et][2], accA[4 + et][3]);
        // ---- kvu: D[c][e] += sum_{n in wave slice} k2t[n][c]*v[n][e], all in registers
        #pragma unroll
        for (int t4 = 0; t4 < 4; ++t4)
            #pragma unroll
            for (int et = 0; et < 4; ++et)
                accK[t4][et] = mfma_16x16x16(ka[t4], vb[et], accK[t4][et]);
    };

    for (int t = g; t < NN / 64; t += 2 * G1) {
        tile(pfA, xsb[0], t + 2 * G1);
        if (t + G1 < NN / 64)            // uniform over the block (t, G1 uniform)
            tile(pfB, xsb[1], t + 3 * G1);
    }
    // ---- flush: cross-wave reduce kvu via LDS, then per-block partials to global
    float* kp = kvu_part + (size_t)(b * G1 + g) * 4096;
    #pragma unroll
    for (int t4 = 0; t4 < 4; ++t4) {
        __syncthreads();
        #pragma unroll
        for (int et = 0; et < 4; ++et)
            #pragma unroll
            for (int r = 0; r < 4; ++r)
                red[w][4 * q + r][16 * et + l15] = accK[t4][et][r];
        __syncthreads();
        #pragma unroll
        for (int l = 0; l < 4; ++l) {
            int idx = tid + 256 * l; int cl = idx >> 6, e = idx & 63;
            kp[(16 * t4 + cl) * 64 + e] =
                red[0][cl][e] + red[1][cl][e] + red[2][cl][e] + red[3][cl][e];
        }
    }
    #pragma unroll
    for (int t4 = 0; t4 < 4; ++t4) {
        float v = ksq_acc[t4];
        v += __shfl_xor(v, 16, 64);
        v += __shfl_xor(v, 32, 64);
        if (q == 0) ksq_red[w][16 * t4 + l15] = v;
    }
    __syncthreads();
    if (tid < 64)
        ksq_part[(size_t)(b * G1 + g) * 64 + tid] =
            ksq_red[0][tid] + ksq_red[1][tid] + ksq_red[2][tid] + ksq_red[3][tid];
}

// ---------------- K2: reduce partials over g; kvw_t[b][d][c] = bf16(inv_k[c]*sum_e kvu[c][e]*w_ln[d][e])
// (unchanged)
__global__ __launch_bounds__(256) void k2_kvw(const float* __restrict__ kvu_part,
        const float* __restrict__ ksq_part, const float* __restrict__ w_ln,
        u16* __restrict__ kvw_t) {
    __shared__ float wln_s[64 * 68];
    __shared__ float kvr[4 * 68];
    __shared__ float ksq_r[64];
    __shared__ float inv_k[4];
    const int tid = threadIdx.x;
    const int c0 = blockIdx.x * 4, b = blockIdx.y;
    #pragma unroll
    for (int lidx = 0; lidx < 16; ++lidx) {
        int idx = tid + 256 * lidx;
        wln_s[(idx >> 6) * 68 + (idx & 63)] = w_ln[idx];
    }
    {   // thread (cl = tid>>6, e = tid&63): sum kvu over g, 8 concurrent chains
        const int cl = tid >> 6, e = tid & 63;
        const float* p = kvu_part + (size_t)b * G1 * 4096 + (c0 + cl) * 64 + e;
        float s[8];
        #pragma unroll
        for (int k = 0; k < 8; ++k) s[k] = 0.f;
        for (int g = 0; g < G1; g += 8) {
            #pragma unroll
            for (int k = 0; k < 8; ++k) s[k] += p[(size_t)(g + k) * 4096];
        }
        kvr[cl * 68 + e] = ((s[0] + s[1]) + (s[2] + s[3])) + ((s[4] + s[5]) + (s[6] + s[7]));
    }
    if (tid < 64) {  // ksq reduce spread over 16 g-partials x 4 c
        const int cl = tid & 3, gp = tid >> 2;
        float s = 0.f;
        #pragma unroll
        for (int k = 0; k < 6; ++k)
            s += ksq_part[(size_t)(b * G1 + gp + 16 * k) * 64 + c0 + cl];
        ksq_r[tid] = s;
    }
    __syncthreads();
    if (tid < 4) {
        float s = 0.f;
        #pragma unroll
        for (int gp = 0; gp < 16; ++gp) s += ksq_r[gp * 4 + tid];
        inv_k[tid] = 1.f / (fmaxf(sqrtf(s), 1e-12f) * 256.f);
    }
    __syncthreads();
    {   // thread (d = tid>>2, cl = tid&3): 64-wide dot, vectorized
        const int d = tid >> 2, cl = tid & 3;
        float s = 0.f;
        #pragma unroll
        for (int e4 = 0; e4 < 16; ++e4) {
            float4 a  = *(const float4*)&kvr[cl * 68 + 4 * e4];
            float4 wv = *(const float4*)&wln_s[d * 68 + 4 * e4];
            s += a.x * wv.x + a.y * wv.y + a.z * wv.z + a.w * wv.w;
        }
        kvw_t[(size_t)b * 4096 + d * 64 + c0 + cl] = f2bf(s * inv_k[cl]);
    }
}

// ---------------- K3: persistent multi-tile; bf16 double-buffered staging with 2-deep
// register prefetch; DPP stats; operand-swapped d-major o/t2 GEMMs; direct register->global
// stores. One barrier/tile (qt + wrow are same-wave-only).
__global__ __launch_bounds__(256) void k3_out(const float* __restrict__ x,
        const u16* __restrict__ w_q_bf, const u16* __restrict__ wvln_bf,
        const float* __restrict__ b_qkv, const float* __restrict__ bias2,
        const u16* __restrict__ kvw_t, float* __restrict__ out) {
    __shared__ u16 xsb[2][64 * SXB];   // x tiles bf16: [c][n], double-buffered
    __shared__ u16 qt[64 * STK];       // q2: [n][c] bf16 (same-wave rows only)
    __shared__ float wrow_s[4][16];    // per-wave w_row redistribution
    const int tid = threadIdx.x;
    const int w = tid >> 6, lane = tid & 63, q = lane >> 4, l15 = lane & 15;
    const int b = blockIdx.y, g = blockIdx.x;
    const float* xb = x + (size_t)b * 64 * NN;
    const int sc = tid >> 4, sn = (tid & 15) << 2;
    const float* xg = xb + (size_t)sc * NN + sn;
    const u16* kvb = kvw_t + (size_t)b * 4096;

    float biasQ[4];
    #pragma unroll
    for (int t4 = 0; t4 < 4; ++t4) biasQ[t4] = b_qkv[16 * t4 + l15];
    float biasO[4][4];   // bias2[d] for d = 16*dt + 4*q + r (d-major accO init)
    #pragma unroll
    for (int dt = 0; dt < 4; ++dt)
        #pragma unroll
        for (int r = 0; r < 4; ++r) biasO[dt][r] = bias2[16 * dt + 4 * q + r];

    float4 pfA[4], pfB[4];
    #pragma unroll
    for (int i = 0; i < 4; ++i)
        pfA[i] = *(const float4*)(xg + (size_t)(16 * i) * NN + g * 64);
    if (g + G3 < NN / 64) {
        #pragma unroll
        for (int i = 0; i < 4; ++i)
            pfB[i] = *(const float4*)(xg + (size_t)(16 * i) * NN + (g + G3) * 64);
    }

    auto tile = [&](float4 (&pfb)[4], u16* __restrict__ xp, int tcur, int tnext) {
        const int n0 = tcur * 64;
        #pragma unroll
        for (int i = 0; i < 4; ++i) {
            int c = 16 * i + sc;
            uint2 pk;
            pk.x = pack2(pfb[i].x, pfb[i].y);
            pk.y = pack2(pfb[i].z, pfb[i].w);
            *(uint2*)&xp[c * SXB + sn] = pk;
        }
        if (tnext < NN / 64) {   // refill 2 tiles ahead; issued before the barrier
            #pragma unroll
            for (int i = 0; i < 4; ++i)
                pfb[i] = *(const float4*)(xg + (size_t)(16 * i) * NN + tnext * 64);
        }
        __syncthreads();   // single barrier per tile
        // ---- GEMM A: accQ = q (n-major, for stats); accO = o = x@wvln^T + bias2 (d-major)
        f32x4_t accQ[4], accO[4];
        #pragma unroll
        for (int t4 = 0; t4 < 4; ++t4)
            accQ[t4] = (f32x4_t){biasQ[t4], biasQ[t4], biasQ[t4], biasQ[t4]};
        #pragma unroll
        for (int dt = 0; dt < 4; ++dt)
            accO[dt] = (f32x4_t){biasO[dt][0], biasO[dt][1], biasO[dt][2], biasO[dt][3]};
        #pragma unroll
        for (int ks = 0; ks < 2; ++ks) {
            union { u16 u[8]; bf16x8_t v; } af;   // x^T[n][c] frag, bf16 direct
            #pragma unroll
            for (int j = 0; j < 8; ++j)
                af.u[j] = xp[(ks * 32 + q * 8 + j) * SXB + 16 * w + l15];
            #pragma unroll
            for (int t4 = 0; t4 < 4; ++t4) {
                bf16x8_t bq = *(const bf16x8_t*)(w_q_bf + (16 * t4 + l15) * 64 + ks * 32 + q * 8);
                accQ[t4] = __builtin_amdgcn_mfma_f32_16x16x32_bf16(af.v, bq, accQ[t4], 0, 0, 0);
            }
            #pragma unroll
            for (int dt = 0; dt < 4; ++dt) {
                bf16x8_t aw = *(const bf16x8_t*)(wvln_bf + (16 * dt + l15) * 64 + ks * 32 + q * 8);
                accO[dt] = __builtin_amdgcn_mfma_f32_16x16x32_bf16(aw, af.v, accO[dt], 0, 0, 0);
            }
        }
        // ---- q stats via DPP: mu, q2s; q2; w_row = 1/max(||q2||, 1e-12*(q2s+eps))
        float mu[4], q2s[4];
        #pragma unroll
        for (int r = 0; r < 4; ++r) {
            float a0 = accQ[0][r], a1 = accQ[1][r], a2 = accQ[2][r], a3 = accQ[3][r];
            float s1 = row_red16(a0 + a1 + a2 + a3);
            float s2 = row_red16(a0 * a0 + a1 * a1 + a2 * a2 + a3 * a3);
            mu[r] = s1 * 0.015625f;
            q2s[r] = s2 - 64.f * mu[r] * mu[r];
        }
        float q2v[4][4];
        float s4[4] = {0.f, 0.f, 0.f, 0.f};
        #pragma unroll
        for (int t4 = 0; t4 < 4; ++t4)
            #pragma unroll
            for (int r = 0; r < 4; ++r) {
                float d = accQ[t4][r] - mu[r];
                float v2 = d * d;
                q2v[t4][r] = v2;
                s4[r] += v2 * v2;
            }
        float w_row[4];
        #pragma unroll
        for (int r = 0; r < 4; ++r) {
            float s = row_red16(s4[r]);
            w_row[r] = 1.f / fmaxf(sqrtf(s), 1e-12f * (q2s[r] + 1e-7f));
        }
        // ---- redistribute w_row: row n=16w+4q+r -> lane col l15 (same wave only)
        if (l15 == 0) {
            #pragma unroll
            for (int r = 0; r < 4; ++r) wrow_s[w][4 * q + r] = w_row[r];
        }
        // ---- q2 -> qt LDS ([n][c] bf16, same-wave rows)
        #pragma unroll
        for (int t4 = 0; t4 < 4; ++t4)
            #pragma unroll
            for (int r = 0; r < 4; ++r)
                qt[(16 * w + 4 * q + r) * STK + 16 * t4 + l15] = f2bf(q2v[t4][r]);
        // ---- GEMM B (d-major): t2[d][n] = sum_c kvw[d][c]-frag * q2[n][c]
        f32x4_t accB[4];
        #pragma unroll
        for (int dt = 0; dt < 4; ++dt) accB[dt] = (f32x4_t){0.f, 0.f, 0.f, 0.f};
        #pragma unroll
        for (int ks = 0; ks < 2; ++ks) {
            union { bf16x8_t v; uint2 h[2]; } b2;   // q2[n][c] frag as B-operand
            const u16* bp = &qt[(16 * w + l15) * STK + ks * 32 + q * 8];
            b2.h[0] = *(const uint2*)bp;
            b2.h[1] = *(const uint2*)(bp + 4);
            #pragma unroll
            for (int dt = 0; dt < 4; ++dt) {
                bf16x8_t ak = *(const bf16x8_t*)(kvb + (16 * dt + l15) * 64 + ks * 32 + q * 8);
                accB[dt] = __builtin_amdgcn_mfma_f32_16x16x32_bf16(ak, b2.v, accB[dt], 0, 0, 0);
            }
        }
        float wr = wrow_s[w][l15];
        // ---- epilogue: out[d][n] = o + w_row[n]*t2, direct register stores
        #pragma unroll
        for (int dt = 0; dt < 4; ++dt) {
            float* op = out + ((size_t)(b * 64 + 16 * dt + 4 * q)) * NN + n0 + 16 * w + l15;
            #pragma unroll
            for (int r = 0; r < 4; ++r)
                op[(size_t)r * NN] = accO[dt][r] + wr * accB[dt][r];
        }
    };

    for (int t = g; t < NN / 64; t += 2 * G3) {
        tile(pfA, xsb[0], t, t + 2 * G3);
        if (t + G3 < NN / 64)            // uniform over the block
            tile(pfB, xsb[1], t + G3, t + 3 * G3);
    }
}

extern "C" void kernel_launch(void* const* d_in, const int* in_sizes, int n_in,
                              void* d_out, int out_size, void* d_ws, size_t ws_size,
                              hipStream_t stream) {
    const float* x     = (const float*)d_in[0];
    const float* w_qkv = (const float*)d_in[1];
    const float* b_qkv = (const float*)d_in[2];
    const float* w_ln  = (const float*)d_in[3];
    const float* b_ln  = (const float*)d_in[4];
    float* out = (float*)d_out;
    char* ws = (char*)d_ws;
    // byte layout (total 12.88 MB, unchanged)
    float* kvu_part = (float*)(ws);                       // 8*96*4096 f32
    float* ksq_part = (float*)(ws + 12582912);            // 8*96*64 f32
    u16*   kvw_t    = (u16*)  (ws + 12779520);            // 8*4096 bf16
    u16*   w_kv_bf  = (u16*)  (ws + 12845056);            // 128*64 bf16
    u16*   w_q_bf   = (u16*)  (ws + 12861440);            // 64*64 bf16
    u16*   wvln_bf  = (u16*)  (ws + 12869632);            // 64*64 bf16
    float* bias2    = (float*)(ws + 12877824);            // 64 f32

    k0_prep<<<dim3(65), dim3(256), 0, stream>>>(w_qkv, b_qkv, w_ln, b_ln,
                                                w_kv_bf, w_q_bf, wvln_bf, bias2);
    k1_kv<<<dim3(G1, 8), dim3(256), 0, stream>>>(x, w_kv_bf, b_qkv, kvu_part, ksq_part);
    k2_kvw<<<dim3(16, 8), dim3(256), 0, stream>>>(kvu_part, ksq_part, w_ln, kvw_t);
    k3_out<<<dim3(G3, 8), dim3(256), 0, stream>>>(x, w_q_bf, wvln_bf, b_qkv, bias2, kvw_t, out);
}

// Round 9
// 303.989 us; speedup vs baseline: 1.3501x; 1.2496x over previous
//
#include <hip/hip_runtime.h>

// ESSAttn bf16-MFMA version. b=8, C=64, H=W=256 (N=65536), fp32 in/out.
// Math (exact refactor of reference):
//   out[b,n,d] = x_col(n)@wvln[d,:] + bias2[d] + w_row[n] * sum_c q2[n,c]*kvw[b][c][d]
//   kvw[c][d]  = inv_k[c] * sum_e kvu[c][e]*w_ln[d][e],  inv_k = 1/(256*max(sqrt(ksq_c),1e-12))
//   kvu[c][e]  = sum_n k2t[n,c]*v[n,e],  ksq_c = sum_n k2t^2
//   k2t = (k-mean_c(k))^2/(k2s+1e-7),  q2 = (q-mean)^2, w_row folds q2 normalizations.
// Round 9: base = round 6 (302.5us best). k3 reverted to round-6 form (round-8's tile-pair
// lambda blew VGPR 120->160, occupancy 10.5%). k1 re-tiled 64c x 128n: halves barriers/n,
// doubles HBM chunk (512B rows), reuses weight frags 2x, doubles the compute window that
// hides the prefetch - at pf[8] (+16 VGPR only), no code duplication (unroll-2 inner loop).
// Both kernels: prefetch issue moved BEFORE the barrier (WAR-safe, widens latency window).

typedef unsigned short u16;
typedef unsigned int u32;
typedef short bf16x8_t __attribute__((ext_vector_type(8)));
typedef short bf16x4_t __attribute__((ext_vector_type(4)));
typedef float f32x4_t __attribute__((ext_vector_type(4)));

#define NN 65536
#define G1 96
#define G3 192   // k3 persistent blocks per batch
#define STK 68   // bf16 qt LDS stride (elements)
#define SXB 68   // bf16 x-tile LDS stride, k3 (64n tiles)
#define SX2 132  // bf16 x-tile LDS stride, k1 (128n tiles; pad 4 -> 2-way-free banks)

static __device__ __forceinline__ u16 f2bf(float f) {
    union { float f; u32 u; } v; v.f = f;
    u32 r = v.u + 0x7FFFu + ((v.u >> 16) & 1u);
    return (u16)(r >> 16);
}
static __device__ __forceinline__ u32 pack2(float a, float b) {
    return (u32)f2bf(a) | ((u32)f2bf(b) << 16);
}
static __device__ __forceinline__ bf16x4_t pack4(float a, float b, float c, float d) {
    uint2 t; t.x = pack2(a, b); t.y = pack2(c, d);
    return __builtin_bit_cast(bf16x4_t, t);
}

// 16-lane (row) sum reduction via DPP: bitwise-identical to xor-butterfly m=1,2,4,8.
template <int CTRL>
static __device__ __forceinline__ float dpp_addf(float x) {
    int y = __builtin_amdgcn_update_dpp(0, __float_as_int(x), CTRL, 0xF, 0xF, false);
    return x + __int_as_float(y);
}
static __device__ __forceinline__ float row_red16(float s) {
    s = dpp_addf<0xB1>(s);    // quad_perm [1,0,3,2]  == xor 1
    s = dpp_addf<0x4E>(s);    // quad_perm [2,3,0,1]  == xor 2
    s = dpp_addf<0x141>(s);   // row_half_mirror      == xor 4 (post quad-sum)
    s = dpp_addf<0x140>(s);   // row_mirror           == xor 8 (post half-sum)
    return s;
}

static __device__ __forceinline__ f32x4_t mfma_16x16x16(bf16x4_t a, bf16x4_t b, f32x4_t c) {
#if __has_builtin(__builtin_amdgcn_mfma_f32_16x16x16bf16_1k)
    return __builtin_amdgcn_mfma_f32_16x16x16bf16_1k(a, b, c, 0, 0, 0);
#else
    f32x4_t d;
    asm("v_mfma_f32_16x16x16_bf16 %0, %1, %2, %3" : "=v"(d) : "v"(a), "v"(b), "v"(c));
    return d;
#endif
}

// ---------------- K0: cast weights to bf16; wvln = w_ln @ w_v; bias2 = w_ln@b_v + b_ln
__global__ void k0_prep(const float* __restrict__ w_qkv, const float* __restrict__ b_qkv,
                        const float* __restrict__ w_ln, const float* __restrict__ b_ln,
                        u16* __restrict__ w_kv_bf, u16* __restrict__ w_q_bf,
                        u16* __restrict__ wvln_bf, float* __restrict__ bias2) {
    int idx = blockIdx.x * 256 + threadIdx.x;
    if (idx < 8192) {                       // rows 64..191 of w_qkv = [w_k | w_v]
        w_kv_bf[idx] = f2bf(w_qkv[4096 + idx]);
    } else if (idx < 12288) {               // rows 0..63 = w_q
        w_q_bf[idx - 8192] = f2bf(w_qkv[idx - 8192]);
    } else if (idx < 16384) {
        int i = idx - 12288; int d = i >> 6, c = i & 63;
        float s = 0.f;
        #pragma unroll 8
        for (int e = 0; e < 64; ++e)
            s += w_ln[d * 64 + e] * w_qkv[(128 + e) * 64 + c];
        wvln_bf[i] = f2bf(s);
    } else if (idx < 16448) {
        int d = idx - 16384;
        float s = b_ln[d];
        #pragma unroll 8
        for (int e = 0; e < 64; ++e)
            s += w_ln[d * 64 + e] * b_qkv[128 + e];
        bias2[d] = s;
    }
}

// ---------------- K1: per (g,b): loop 128n-tiles; bf16 double-buffered staging (512B HBM
// rows); MFMA k|v GEMM per 16n group (wave owns 32n); DPP stats; in-register kvu via
// 16x16x16 MFMA; cross-wave reduce + flush at end. One barrier per 128n tile.
__global__ __launch_bounds__(256) void k1_kv(const float* __restrict__ x,
        const u16* __restrict__ w_kv_bf, const float* __restrict__ b_qkv,
        float* __restrict__ kvu_part, float* __restrict__ ksq_part) {
    __shared__ u16 xsb[2][64 * SX2];    // x tiles bf16: [c][128n], double-buffered (33.8KB)
    __shared__ float red[4][16][64];    // cross-wave kvu reduction (flush only)
    __shared__ float ksq_red[4][64];
    const int tid = threadIdx.x;
    const int w = tid >> 6, lane = tid & 63, q = lane >> 4, l15 = lane & 15;
    const int b = blockIdx.y, g = blockIdx.x;
    const float* xb = x + (size_t)b * 64 * NN;
    const int rc = tid >> 2;          // staging channel row (64 rows, 4 threads/row)
    const int nq = (tid & 3) << 5;    // staging n offset (32 consecutive n per thread)
    const float* xg = xb + (size_t)rc * NN + nq;

    float bias[8];
    #pragma unroll
    for (int t8 = 0; t8 < 8; ++t8) bias[t8] = b_qkv[64 + 16 * t8 + l15];

    f32x4_t accK[4][4];   // kvu: [c-tile][e-tile], wave-local over its n slices
    #pragma unroll
    for (int t4 = 0; t4 < 4; ++t4)
        #pragma unroll
        for (int et = 0; et < 4; ++et) accK[t4][et] = (f32x4_t){0.f, 0.f, 0.f, 0.f};
    float ksq_acc[4] = {0.f, 0.f, 0.f, 0.f};

    // prefetch first tile (8 float4 = this thread's 32 consecutive n on its channel row)
    float4 pf[8];
    #pragma unroll
    for (int i = 0; i < 8; ++i)
        pf[i] = *(const float4*)(xg + (size_t)g * 128 + 4 * i);

    int p = 0;
    for (int t = g; t < NN / 128; t += G1) {
        // ---- commit prefetched tile to LDS as bf16
        u16* xp = xsb[p];
        #pragma unroll
        for (int i = 0; i < 8; ++i) {
            uint2 pk;
            pk.x = pack2(pf[i].x, pf[i].y);
            pk.y = pack2(pf[i].z, pf[i].w);
            *(uint2*)&xp[rc * SX2 + nq + 4 * i] = pk;
        }
        // ---- issue next tile's loads BEFORE the barrier (widens latency window)
        if (t + G1 < NN / 128) {
            #pragma unroll
            for (int i = 0; i < 8; ++i)
                pf[i] = *(const float4*)(xg + (size_t)(t + G1) * 128 + 4 * i);
        }
        __syncthreads();   // single barrier per 128n tile (double-buffered)
        // ---- wave w owns n columns 32w..32w+31, processed as 2 groups of 16
        #pragma unroll
        for (int ns = 0; ns < 2; ++ns) {
            // GEMM A: D[n][dcol], dcol 0..63 = k, 64..127 = v (K = 64 channels)
            f32x4_t accA[8];
            #pragma unroll
            for (int t8 = 0; t8 < 8; ++t8)
                accA[t8] = (f32x4_t){bias[t8], bias[t8], bias[t8], bias[t8]};
            #pragma unroll
            for (int ks = 0; ks < 2; ++ks) {
                union { u16 u[8]; bf16x8_t v; } af;   // x^T[n][c] frag, bf16 direct
                #pragma unroll
                for (int j = 0; j < 8; ++j)
                    af.u[j] = xp[(ks * 32 + q * 8 + j) * SX2 + 32 * w + 16 * ns + l15];
                #pragma unroll
                for (int t8 = 0; t8 < 8; ++t8) {
                    bf16x8_t bf = *(const bf16x8_t*)(w_kv_bf + (16 * t8 + l15) * 64 + ks * 32 + q * 8);
                    accA[t8] = __builtin_amdgcn_mfma_f32_16x16x32_bf16(af.v, bf, accA[t8], 0, 0, 0);
                }
            }
            // k stats per row (row = 4q + r): mean, 1/(k2s+eps) via DPP row reductions
            float mu[4], rin[4];
            #pragma unroll
            for (int r = 0; r < 4; ++r) {
                float a0 = accA[0][r], a1 = accA[1][r], a2 = accA[2][r], a3 = accA[3][r];
                float s1 = row_red16(a0 + a1 + a2 + a3);
                float s2 = row_red16(a0 * a0 + a1 * a1 + a2 * a2 + a3 * a3);
                mu[r] = s1 * 0.015625f;
                rin[r] = 1.f / (s2 - 64.f * mu[r] * mu[r] + 1e-7f);
            }
            // k2t, v -> in-register bf16 fragments (accA layout == 16x16x16 operand layout)
            bf16x4_t ka[4], vb[4];
            #pragma unroll
            for (int t4 = 0; t4 < 4; ++t4) {
                float t2v[4];
                #pragma unroll
                for (int r = 0; r < 4; ++r) {
                    float d = accA[t4][r] - mu[r];
                    float t2 = d * d * rin[r];
                    t2v[r] = t2;
                    ksq_acc[t4] += t2 * t2;
                }
                ka[t4] = pack4(t2v[0], t2v[1], t2v[2], t2v[3]);
            }
            #pragma unroll
            for (int et = 0; et < 4; ++et)
                vb[et] = pack4(accA[4 + et][0], accA[4 + et][1], accA[4 + et][2], accA[4 + et][3]);
            // kvu: D[c][e] += sum_{n in group} k2t[n][c]*v[n][e], all in registers
            #pragma unroll
            for (int t4 = 0; t4 < 4; ++t4)
                #pragma unroll
                for (int et = 0; et < 4; ++et)
                    accK[t4][et] = mfma_16x16x16(ka[t4], vb[et], accK[t4][et]);
        }
        p ^= 1;
    }
    // ---- flush: cross-wave reduce kvu via LDS, then per-block partials to global
    float* kp = kvu_part + (size_t)(b * G1 + g) * 4096;
    #pragma unroll
    for (int t4 = 0; t4 < 4; ++t4) {
        __syncthreads();
        #pragma unroll
        for (int et = 0; et < 4; ++et)
            #pragma unroll
            for (int r = 0; r < 4; ++r)
                red[w][4 * q + r][16 * et + l15] = accK[t4][et][r];
        __syncthreads();
        #pragma unroll
        for (int l = 0; l < 4; ++l) {
            int idx = tid + 256 * l; int cl = idx >> 6, e = idx & 63;
            kp[(16 * t4 + cl) * 64 + e] =
                red[0][cl][e] + red[1][cl][e] + red[2][cl][e] + red[3][cl][e];
        }
    }
    #pragma unroll
    for (int t4 = 0; t4 < 4; ++t4) {
        float v = ksq_acc[t4];
        v += __shfl_xor(v, 16, 64);
        v += __shfl_xor(v, 32, 64);
        if (q == 0) ksq_red[w][16 * t4 + l15] = v;
    }
    __syncthreads();
    if (tid < 64)
        ksq_part[(size_t)(b * G1 + g) * 64 + tid] =
            ksq_red[0][tid] + ksq_red[1][tid] + ksq_red[2][tid] + ksq_red[3][tid];
}

// ---------------- K2: reduce partials over g; kvw_t[b][d][c] = bf16(inv_k[c]*sum_e kvu[c][e]*w_ln[d][e])
// (unchanged)
__global__ __launch_bounds__(256) void k2_kvw(const float* __restrict__ kvu_part,
        const float* __restrict__ ksq_part, const float* __restrict__ w_ln,
        u16* __restrict__ kvw_t) {
    __shared__ float wln_s[64 * 68];
    __shared__ float kvr[4 * 68];
    __shared__ float ksq_r[64];
    __shared__ float inv_k[4];
    const int tid = threadIdx.x;
    const int c0 = blockIdx.x * 4, b = blockIdx.y;
    #pragma unroll
    for (int lidx = 0; lidx < 16; ++lidx) {
        int idx = tid + 256 * lidx;
        wln_s[(idx >> 6) * 68 + (idx & 63)] = w_ln[idx];
    }
    {   // thread (cl = tid>>6, e = tid&63): sum kvu over g, 8 concurrent chains
        const int cl = tid >> 6, e = tid & 63;
        const float* p = kvu_part + (size_t)b * G1 * 4096 + (c0 + cl) * 64 + e;
        float s[8];
        #pragma unroll
        for (int k = 0; k < 8; ++k) s[k] = 0.f;
        for (int g = 0; g < G1; g += 8) {
            #pragma unroll
            for (int k = 0; k < 8; ++k) s[k] += p[(size_t)(g + k) * 4096];
        }
        kvr[cl * 68 + e] = ((s[0] + s[1]) + (s[2] + s[3])) + ((s[4] + s[5]) + (s[6] + s[7]));
    }
    if (tid < 64) {  // ksq reduce spread over 16 g-partials x 4 c
        const int cl = tid & 3, gp = tid >> 2;
        float s = 0.f;
        #pragma unroll
        for (int k = 0; k < 6; ++k)
            s += ksq_part[(size_t)(b * G1 + gp + 16 * k) * 64 + c0 + cl];
        ksq_r[tid] = s;
    }
    __syncthreads();
    if (tid < 4) {
        float s = 0.f;
        #pragma unroll
        for (int gp = 0; gp < 16; ++gp) s += ksq_r[gp * 4 + tid];
        inv_k[tid] = 1.f / (fmaxf(sqrtf(s), 1e-12f) * 256.f);
    }
    __syncthreads();
    {   // thread (d = tid>>2, cl = tid&3): 64-wide dot, vectorized
        const int d = tid >> 2, cl = tid & 3;
        float s = 0.f;
        #pragma unroll
        for (int e4 = 0; e4 < 16; ++e4) {
            float4 a  = *(const float4*)&kvr[cl * 68 + 4 * e4];
            float4 wv = *(const float4*)&wln_s[d * 68 + 4 * e4];
            s += a.x * wv.x + a.y * wv.y + a.z * wv.z + a.w * wv.w;
        }
        kvw_t[(size_t)b * 4096 + d * 64 + c0 + cl] = f2bf(s * inv_k[cl]);
    }
}

// ---------------- K3: persistent multi-tile (round-6 form); bf16 double-buffered staging;
// DPP stats; operand-swapped d-major o/t2 GEMMs; direct register->global stores.
// One barrier/tile; prefetch issue moved before the barrier.
__global__ __launch_bounds__(256) void k3_out(const float* __restrict__ x,
        const u16* __restrict__ w_q_bf, const u16* __restrict__ wvln_bf,
        const float* __restrict__ b_qkv, const float* __restrict__ bias2,
        const u16* __restrict__ kvw_t, float* __restrict__ out) {
    __shared__ u16 xsb[2][64 * SXB];   // x tiles bf16: [c][n], double-buffered
    __shared__ u16 qt[64 * STK];       // q2: [n][c] bf16 (same-wave rows only)
    __shared__ float wrow_s[4][16];    // per-wave w_row redistribution
    const int tid = threadIdx.x;
    const int w = tid >> 6, lane = tid & 63, q = lane >> 4, l15 = lane & 15;
    const int b = blockIdx.y, g = blockIdx.x;
    const float* xb = x + (size_t)b * 64 * NN;
    const int sc = tid >> 4, sn = (tid & 15) << 2;
    const float* xg = xb + (size_t)sc * NN + sn;
    const u16* kvb = kvw_t + (size_t)b * 4096;

    float biasQ[4];
    #pragma unroll
    for (int t4 = 0; t4 < 4; ++t4) biasQ[t4] = b_qkv[16 * t4 + l15];
    float biasO[4][4];   // bias2[d] for d = 16*dt + 4*q + r (d-major accO init)
    #pragma unroll
    for (int dt = 0; dt < 4; ++dt)
        #pragma unroll
        for (int r = 0; r < 4; ++r) biasO[dt][r] = bias2[16 * dt + 4 * q + r];

    // prefetch first tile into registers
    float4 pf[4];
    #pragma unroll
    for (int i = 0; i < 4; ++i)
        pf[i] = *(const float4*)(xg + (size_t)(16 * i) * NN + g * 64);

    int p = 0;
    for (int t = g; t < NN / 64; t += G3) {
        const int n0 = t * 64;
        // ---- commit prefetched tile to LDS as bf16
        u16* xp = xsb[p];
        #pragma unroll
        for (int i = 0; i < 4; ++i) {
            int c = 16 * i + sc;
            uint2 pk;
            pk.x = pack2(pf[i].x, pf[i].y);
            pk.y = pack2(pf[i].z, pf[i].w);
            *(uint2*)&xp[c * SXB + sn] = pk;
        }
        // ---- issue next tile's loads BEFORE the barrier
        if (t + G3 < NN / 64) {
            #pragma unroll
            for (int i = 0; i < 4; ++i)
                pf[i] = *(const float4*)(xg + (size_t)(16 * i) * NN + (t + G3) * 64);
        }
        __syncthreads();   // single barrier per tile
        // ---- GEMM A: accQ = q (n-major, for stats); accO = o = x@wvln^T + bias2 (d-major)
        f32x4_t accQ[4], accO[4];
        #pragma unroll
        for (int t4 = 0; t4 < 4; ++t4)
            accQ[t4] = (f32x4_t){biasQ[t4], biasQ[t4], biasQ[t4], biasQ[t4]};
        #pragma unroll
        for (int dt = 0; dt < 4; ++dt)
            accO[dt] = (f32x4_t){biasO[dt][0], biasO[dt][1], biasO[dt][2], biasO[dt][3]};
        #pragma unroll
        for (int ks = 0; ks < 2; ++ks) {
            union { u16 u[8]; bf16x8_t v; } af;   // x^T[n][c] frag, bf16 direct
            #pragma unroll
            for (int j = 0; j < 8; ++j)
                af.u[j] = xp[(ks * 32 + q * 8 + j) * SXB + 16 * w + l15];
            #pragma unroll
            for (int t4 = 0; t4 < 4; ++t4) {
                bf16x8_t bq = *(const bf16x8_t*)(w_q_bf + (16 * t4 + l15) * 64 + ks * 32 + q * 8);
                accQ[t4] = __builtin_amdgcn_mfma_f32_16x16x32_bf16(af.v, bq, accQ[t4], 0, 0, 0);
            }
            #pragma unroll
            for (int dt = 0; dt < 4; ++dt) {
                bf16x8_t aw = *(const bf16x8_t*)(wvln_bf + (16 * dt + l15) * 64 + ks * 32 + q * 8);
                accO[dt] = __builtin_amdgcn_mfma_f32_16x16x32_bf16(aw, af.v, accO[dt], 0, 0, 0);
            }
        }
        // ---- q stats via DPP: mu, q2s; q2; w_row = 1/max(||q2||, 1e-12*(q2s+eps))
        float mu[4], q2s[4];
        #pragma unroll
        for (int r = 0; r < 4; ++r) {
            float a0 = accQ[0][r], a1 = accQ[1][r], a2 = accQ[2][r], a3 = accQ[3][r];
            float s1 = row_red16(a0 + a1 + a2 + a3);
            float s2 = row_red16(a0 * a0 + a1 * a1 + a2 * a2 + a3 * a3);
            mu[r] = s1 * 0.015625f;
            q2s[r] = s2 - 64.f * mu[r] * mu[r];
        }
        float q2v[4][4];
        float s4[4] = {0.f, 0.f, 0.f, 0.f};
        #pragma unroll
        for (int t4 = 0; t4 < 4; ++t4)
            #pragma unroll
            for (int r = 0; r < 4; ++r) {
                float d = accQ[t4][r] - mu[r];
                float v2 = d * d;
                q2v[t4][r] = v2;
                s4[r] += v2 * v2;
            }
        float w_row[4];
        #pragma unroll
        for (int r = 0; r < 4; ++r) {
            float s = row_red16(s4[r]);
            w_row[r] = 1.f / fmaxf(sqrtf(s), 1e-12f * (q2s[r] + 1e-7f));
        }
        // ---- redistribute w_row: row n=16w+4q+r -> lane col l15 (same wave only)
        if (l15 == 0) {
            #pragma unroll
            for (int r = 0; r < 4; ++r) wrow_s[w][4 * q + r] = w_row[r];
        }
        // ---- q2 -> qt LDS ([n][c] bf16, same-wave rows)
        #pragma unroll
        for (int t4 = 0; t4 < 4; ++t4)
            #pragma unroll
            for (int r = 0; r < 4; ++r)
                qt[(16 * w + 4 * q + r) * STK + 16 * t4 + l15] = f2bf(q2v[t4][r]);
        // ---- GEMM B (d-major): t2[d][n] = sum_c kvw[d][c]-frag * q2[n][c]
        f32x4_t accB[4];
        #pragma unroll
        for (int dt = 0; dt < 4; ++dt) accB[dt] = (f32x4_t){0.f, 0.f, 0.f, 0.f};
        #pragma unroll
        for (int ks = 0; ks < 2; ++ks) {
            union { bf16x8_t v; uint2 h[2]; } b2;   // q2[n][c] frag as B-operand
            const u16* bp = &qt[(16 * w + l15) * STK + ks * 32 + q * 8];
            b2.h[0] = *(const uint2*)bp;
            b2.h[1] = *(const uint2*)(bp + 4);
            #pragma unroll
            for (int dt = 0; dt < 4; ++dt) {
                bf16x8_t ak = *(const bf16x8_t*)(kvb + (16 * dt + l15) * 64 + ks * 32 + q * 8);
                accB[dt] = __builtin_amdgcn_mfma_f32_16x16x32_bf16(ak, b2.v, accB[dt], 0, 0, 0);
            }
        }
        float wr = wrow_s[w][l15];
        // ---- epilogue: out[d][n] = o + w_row[n]*t2, direct register stores
        #pragma unroll
        for (int dt = 0; dt < 4; ++dt) {
            float* op = out + ((size_t)(b * 64 + 16 * dt + 4 * q)) * NN + n0 + 16 * w + l15;
            #pragma unroll
            for (int r = 0; r < 4; ++r)
                op[(size_t)r * NN] = accO[dt][r] + wr * accB[dt][r];
        }
        p ^= 1;
    }
}

extern "C" void kernel_launch(void* const* d_in, const int* in_sizes, int n_in,
                              void* d_out, int out_size, void* d_ws, size_t ws_size,
                              hipStream_t stream) {
    const float* x     = (const float*)d_in[0];
    const float* w_qkv = (const float*)d_in[1];
    const float* b_qkv = (const float*)d_in[2];
    const float* w_ln  = (const float*)d_in[3];
    const float* b_ln  = (const float*)d_in[4];
    float* out = (float*)d_out;
    char* ws = (char*)d_ws;
    // byte layout (total 12.88 MB, unchanged)
    float* kvu_part = (float*)(ws);                       // 8*96*4096 f32
    float* ksq_part = (float*)(ws + 12582912);            // 8*96*64 f32
    u16*   kvw_t    = (u16*)  (ws + 12779520);            // 8*4096 bf16
    u16*   w_kv_bf  = (u16*)  (ws + 12845056);            // 128*64 bf16
    u16*   w_q_bf   = (u16*)  (ws + 12861440);            // 64*64 bf16
    u16*   wvln_bf  = (u16*)  (ws + 12869632);            // 64*64 bf16
    float* bias2    = (float*)(ws + 12877824);            // 64 f32

    k0_prep<<<dim3(65), dim3(256), 0, stream>>>(w_qkv, b_qkv, w_ln, b_ln,
                                                w_kv_bf, w_q_bf, wvln_bf, bias2);
    k1_kv<<<dim3(G1, 8), dim3(256), 0, stream>>>(x, w_kv_bf, b_qkv, kvu_part, ksq_part);
    k2_kvw<<<dim3(16, 8), dim3(256), 0, stream>>>(kvu_part, ksq_part, w_ln, kvw_t);
    k3_out<<<dim3(G3, 8), dim3(256), 0, stream>>>(x, w_q_bf, wvln_bf, b_qkv, bias2, kvw_t, out);
}

// Round 10
// 303.637 us; speedup vs baseline: 1.3517x; 1.0012x over previous
//
#include <hip/hip_runtime.h>

// ESSAttn bf16-MFMA version. b=8, C=64, H=W=256 (N=65536), fp32 in/out.
// Math (exact refactor of reference):
//   out[b,n,d] = x_col(n)@wvln[d,:] + bias2[d] + w_row[n] * sum_c q2[n,c]*kvw[b][c][d]
//   kvw[c][d]  = inv_k[c] * sum_e kvu[c][e]*w_ln[d][e],  inv_k = 1/(256*max(sqrt(ksq_c),1e-12))
//   kvu[c][e]  = sum_n k2t[n,c]*v[n,e],  ksq_c = sum_n k2t^2
//   k2t = (k-mean_c(k))^2/(k2s+1e-7),  q2 = (q-mean)^2, w_row folds q2 normalizations.
// Round 10: BARRIER-FREE main loops. Diagnosis: k1/k3 waves stalled ~70% (VALUBusy 30%,
// x is L3-resident so not HBM-latency) because __syncthreads phase-locks all 12 waves/CU
// into simultaneous LDS-commit/lgkmcnt stalls. No cross-wave data dep exists in either
// loop (kvu per-wave, qt/wrow same-wave), so each wave now stages ITS OWN n-columns into
// a private LDS strip (k1: 64c x 32n, 8 lanes/row; k3: 64c x 16n, 4 lanes/row), single-
// buffered (DS ops in-order per wave). Zero __syncthreads in the loops; waves free-run.

typedef unsigned short u16;
typedef unsigned int u32;
typedef short bf16x8_t __attribute__((ext_vector_type(8)));
typedef short bf16x4_t __attribute__((ext_vector_type(4)));
typedef float f32x4_t __attribute__((ext_vector_type(4)));

#define NN 65536
#define G1 96
#define G3 192   // k3 persistent blocks per batch
#define STK 68   // bf16 qt LDS stride (elements)
#define SWK 36   // k1 per-wave x strip stride: 32n + 4 pad (mult of 4 -> 8B-aligned writes)
#define SW3 20   // k3 per-wave x strip stride: 16n + 4 pad

static __device__ __forceinline__ u16 f2bf(float f) {
    union { float f; u32 u; } v; v.f = f;
    u32 r = v.u + 0x7FFFu + ((v.u >> 16) & 1u);
    return (u16)(r >> 16);
}
static __device__ __forceinline__ u32 pack2(float a, float b) {
    return (u32)f2bf(a) | ((u32)f2bf(b) << 16);
}
static __device__ __forceinline__ bf16x4_t pack4(float a, float b, float c, float d) {
    uint2 t; t.x = pack2(a, b); t.y = pack2(c, d);
    return __builtin_bit_cast(bf16x4_t, t);
}

// 16-lane (row) sum reduction via DPP: bitwise-identical to xor-butterfly m=1,2,4,8.
template <int CTRL>
static __device__ __forceinline__ float dpp_addf(float x) {
    int y = __builtin_amdgcn_update_dpp(0, __float_as_int(x), CTRL, 0xF, 0xF, false);
    return x + __int_as_float(y);
}
static __device__ __forceinline__ float row_red16(float s) {
    s = dpp_addf<0xB1>(s);    // quad_perm [1,0,3,2]  == xor 1
    s = dpp_addf<0x4E>(s);    // quad_perm [2,3,0,1]  == xor 2
    s = dpp_addf<0x141>(s);   // row_half_mirror      == xor 4 (post quad-sum)
    s = dpp_addf<0x140>(s);   // row_mirror           == xor 8 (post half-sum)
    return s;
}

static __device__ __forceinline__ f32x4_t mfma_16x16x16(bf16x4_t a, bf16x4_t b, f32x4_t c) {
#if __has_builtin(__builtin_amdgcn_mfma_f32_16x16x16bf16_1k)
    return __builtin_amdgcn_mfma_f32_16x16x16bf16_1k(a, b, c, 0, 0, 0);
#else
    f32x4_t d;
    asm("v_mfma_f32_16x16x16_bf16 %0, %1, %2, %3" : "=v"(d) : "v"(a), "v"(b), "v"(c));
    return d;
#endif
}

// ---------------- K0: cast weights to bf16; wvln = w_ln @ w_v; bias2 = w_ln@b_v + b_ln
__global__ void k0_prep(const float* __restrict__ w_qkv, const float* __restrict__ b_qkv,
                        const float* __restrict__ w_ln, const float* __restrict__ b_ln,
                        u16* __restrict__ w_kv_bf, u16* __restrict__ w_q_bf,
                        u16* __restrict__ wvln_bf, float* __restrict__ bias2) {
    int idx = blockIdx.x * 256 + threadIdx.x;
    if (idx < 8192) {                       // rows 64..191 of w_qkv = [w_k | w_v]
        w_kv_bf[idx] = f2bf(w_qkv[4096 + idx]);
    } else if (idx < 12288) {               // rows 0..63 = w_q
        w_q_bf[idx - 8192] = f2bf(w_qkv[idx - 8192]);
    } else if (idx < 16384) {
        int i = idx - 12288; int d = i >> 6, c = i & 63;
        float s = 0.f;
        #pragma unroll 8
        for (int e = 0; e < 64; ++e)
            s += w_ln[d * 64 + e] * w_qkv[(128 + e) * 64 + c];
        wvln_bf[i] = f2bf(s);
    } else if (idx < 16448) {
        int d = idx - 16384;
        float s = b_ln[d];
        #pragma unroll 8
        for (int e = 0; e < 64; ++e)
            s += w_ln[d * 64 + e] * b_qkv[128 + e];
        bias2[d] = s;
    }
}

// ---------------- K1: per (g,b): loop 128n-tiles; EACH WAVE stages its own 64c x 32n strip
// (private LDS, single-buffered, no barriers); MFMA k|v GEMM per 16n group; DPP stats;
// in-register kvu via 16x16x16 MFMA; cross-wave reduce + flush at end (barriers only there).
__global__ __launch_bounds__(256) void k1_kv(const float* __restrict__ x,
        const u16* __restrict__ w_kv_bf, const float* __restrict__ b_qkv,
        float* __restrict__ kvu_part, float* __restrict__ ksq_part) {
    __shared__ u16 xw[4][64 * SWK];     // per-wave x strips bf16: [c][32n]
    __shared__ float red[4][16][64];    // cross-wave kvu reduction (flush only)
    __shared__ float ksq_red[4][64];
    const int tid = threadIdx.x;
    const int w = tid >> 6, lane = tid & 63, q = lane >> 4, l15 = lane & 15;
    const int b = blockIdx.y, g = blockIdx.x;
    const float* xb = x + (size_t)b * 64 * NN;
    // staging: 8 lanes/row, 8 rows/instr; lane covers rows (lane>>3)+8i, floats (lane&7)*4
    const int h8 = lane >> 3, c7 = lane & 7;
    const float* xgw = xb + (size_t)h8 * NN + 32 * w + 4 * c7;
    u16* xs = xw[w];
    const int sbase = h8 * SWK + 4 * c7;   // LDS element offset for i=0 (rows += 8*SWK)

    float bias[8];
    #pragma unroll
    for (int t8 = 0; t8 < 8; ++t8) bias[t8] = b_qkv[64 + 16 * t8 + l15];

    f32x4_t accK[4][4];   // kvu: [c-tile][e-tile], wave-local over its n slices
    #pragma unroll
    for (int t4 = 0; t4 < 4; ++t4)
        #pragma unroll
        for (int et = 0; et < 4; ++et) accK[t4][et] = (f32x4_t){0.f, 0.f, 0.f, 0.f};
    float ksq_acc[4] = {0.f, 0.f, 0.f, 0.f};

    // prefetch first tile (8 float4: rows h8+8i of this wave's 32n columns)
    float4 pf[8];
    #pragma unroll
    for (int i = 0; i < 8; ++i)
        pf[i] = *(const float4*)(xgw + (size_t)(8 * i) * NN + (size_t)g * 128);

    for (int t = g; t < NN / 128; t += G1) {
        // ---- commit prefetched strip to private LDS as bf16 (waits vmcnt; no barrier)
        #pragma unroll
        for (int i = 0; i < 8; ++i) {
            uint2 pk;
            pk.x = pack2(pf[i].x, pf[i].y);
            pk.y = pack2(pf[i].z, pf[i].w);
            *(uint2*)&xs[sbase + 8 * i * SWK] = pk;
        }
        // ---- issue next tile's loads; consumed at next commit (full-tile window)
        if (t + G1 < NN / 128) {
            #pragma unroll
            for (int i = 0; i < 8; ++i)
                pf[i] = *(const float4*)(xgw + (size_t)(8 * i) * NN + (size_t)(t + G1) * 128);
        }
        // ---- wave w owns n columns [t*128+32w, +32), processed as 2 groups of 16
        #pragma unroll
        for (int ns = 0; ns < 2; ++ns) {
            // GEMM A: D[n][dcol], dcol 0..63 = k, 64..127 = v (K = 64 channels)
            f32x4_t accA[8];
            #pragma unroll
            for (int t8 = 0; t8 < 8; ++t8)
                accA[t8] = (f32x4_t){bias[t8], bias[t8], bias[t8], bias[t8]};
            #pragma unroll
            for (int ks = 0; ks < 2; ++ks) {
                union { u16 u[8]; bf16x8_t v; } af;   // x^T[n][c] frag (same-wave LDS)
                #pragma unroll
                for (int j = 0; j < 8; ++j)
                    af.u[j] = xs[(ks * 32 + q * 8 + j) * SWK + 16 * ns + l15];
                #pragma unroll
                for (int t8 = 0; t8 < 8; ++t8) {
                    bf16x8_t bf = *(const bf16x8_t*)(w_kv_bf + (16 * t8 + l15) * 64 + ks * 32 + q * 8);
                    accA[t8] = __builtin_amdgcn_mfma_f32_16x16x32_bf16(af.v, bf, accA[t8], 0, 0, 0);
                }
            }
            // k stats per row (row = 4q + r): mean, 1/(k2s+eps) via DPP row reductions
            float mu[4], rin[4];
            #pragma unroll
            for (int r = 0; r < 4; ++r) {
                float a0 = accA[0][r], a1 = accA[1][r], a2 = accA[2][r], a3 = accA[3][r];
                float s1 = row_red16(a0 + a1 + a2 + a3);
                float s2 = row_red16(a0 * a0 + a1 * a1 + a2 * a2 + a3 * a3);
                mu[r] = s1 * 0.015625f;
                rin[r] = 1.f / (s2 - 64.f * mu[r] * mu[r] + 1e-7f);
            }
            // k2t, v -> in-register bf16 fragments (accA layout == 16x16x16 operand layout)
            bf16x4_t ka[4], vb[4];
            #pragma unroll
            for (int t4 = 0; t4 < 4; ++t4) {
                float t2v[4];
                #pragma unroll
                for (int r = 0; r < 4; ++r) {
                    float d = accA[t4][r] - mu[r];
                    float t2 = d * d * rin[r];
                    t2v[r] = t2;
                    ksq_acc[t4] += t2 * t2;
                }
                ka[t4] = pack4(t2v[0], t2v[1], t2v[2], t2v[3]);
            }
            #pragma unroll
            for (int et = 0; et < 4; ++et)
                vb[et] = pack4(accA[4 + et][0], accA[4 + et][1], accA[4 + et][2], accA[4 + et][3]);
            // kvu: D[c][e] += sum_{n in group} k2t[n][c]*v[n][e], all in registers
            #pragma unroll
            for (int t4 = 0; t4 < 4; ++t4)
                #pragma unroll
                for (int et = 0; et < 4; ++et)
                    accK[t4][et] = mfma_16x16x16(ka[t4], vb[et], accK[t4][et]);
        }
    }
    // ---- flush: cross-wave reduce kvu via LDS, then per-block partials to global
    float* kp = kvu_part + (size_t)(b * G1 + g) * 4096;
    #pragma unroll
    for (int t4 = 0; t4 < 4; ++t4) {
        __syncthreads();
        #pragma unroll
        for (int et = 0; et < 4; ++et)
            #pragma unroll
            for (int r = 0; r < 4; ++r)
                red[w][4 * q + r][16 * et + l15] = accK[t4][et][r];
        __syncthreads();
        #pragma unroll
        for (int l = 0; l < 4; ++l) {
            int idx = tid + 256 * l; int cl = idx >> 6, e = idx & 63;
            kp[(16 * t4 + cl) * 64 + e] =
                red[0][cl][e] + red[1][cl][e] + red[2][cl][e] + red[3][cl][e];
        }
    }
    #pragma unroll
    for (int t4 = 0; t4 < 4; ++t4) {
        float v = ksq_acc[t4];
        v += __shfl_xor(v, 16, 64);
        v += __shfl_xor(v, 32, 64);
        if (q == 0) ksq_red[w][16 * t4 + l15] = v;
    }
    __syncthreads();
    if (tid < 64)
        ksq_part[(size_t)(b * G1 + g) * 64 + tid] =
            ksq_red[0][tid] + ksq_red[1][tid] + ksq_red[2][tid] + ksq_red[3][tid];
}

// ---------------- K2: reduce partials over g; kvw_t[b][d][c] = bf16(inv_k[c]*sum_e kvu[c][e]*w_ln[d][e])
// (unchanged)
__global__ __launch_bounds__(256) void k2_kvw(const float* __restrict__ kvu_part,
        const float* __restrict__ ksq_part, const float* __restrict__ w_ln,
        u16* __restrict__ kvw_t) {
    __shared__ float wln_s[64 * 68];
    __shared__ float kvr[4 * 68];
    __shared__ float ksq_r[64];
    __shared__ float inv_k[4];
    const int tid = threadIdx.x;
    const int c0 = blockIdx.x * 4, b = blockIdx.y;
    #pragma unroll
    for (int lidx = 0; lidx < 16; ++lidx) {
        int idx = tid + 256 * lidx;
        wln_s[(idx >> 6) * 68 + (idx & 63)] = w_ln[idx];
    }
    {   // thread (cl = tid>>6, e = tid&63): sum kvu over g, 8 concurrent chains
        const int cl = tid >> 6, e = tid & 63;
        const float* p = kvu_part + (size_t)b * G1 * 4096 + (c0 + cl) * 64 + e;
        float s[8];
        #pragma unroll
        for (int k = 0; k < 8; ++k) s[k] = 0.f;
        for (int g = 0; g < G1; g += 8) {
            #pragma unroll
            for (int k = 0; k < 8; ++k) s[k] += p[(size_t)(g + k) * 4096];
        }
        kvr[cl * 68 + e] = ((s[0] + s[1]) + (s[2] + s[3])) + ((s[4] + s[5]) + (s[6] + s[7]));
    }
    if (tid < 64) {  // ksq reduce spread over 16 g-partials x 4 c
        const int cl = tid & 3, gp = tid >> 2;
        float s = 0.f;
        #pragma unroll
        for (int k = 0; k < 6; ++k)
            s += ksq_part[(size_t)(b * G1 + gp + 16 * k) * 64 + c0 + cl];
        ksq_r[tid] = s;
    }
    __syncthreads();
    if (tid < 4) {
        float s = 0.f;
        #pragma unroll
        for (int gp = 0; gp < 16; ++gp) s += ksq_r[gp * 4 + tid];
        inv_k[tid] = 1.f / (fmaxf(sqrtf(s), 1e-12f) * 256.f);
    }
    __syncthreads();
    {   // thread (d = tid>>2, cl = tid&3): 64-wide dot, vectorized
        const int d = tid >> 2, cl = tid & 3;
        float s = 0.f;
        #pragma unroll
        for (int e4 = 0; e4 < 16; ++e4) {
            float4 a  = *(const float4*)&kvr[cl * 68 + 4 * e4];
            float4 wv = *(const float4*)&wln_s[d * 68 + 4 * e4];
            s += a.x * wv.x + a.y * wv.y + a.z * wv.z + a.w * wv.w;
        }
        kvw_t[(size_t)b * 4096 + d * 64 + c0 + cl] = f2bf(s * inv_k[cl]);
    }
}

// ---------------- K3: persistent multi-tile; EACH WAVE stages its own 64c x 16n strip
// (private LDS, single-buffered); DPP stats; operand-swapped d-major o/t2 GEMMs; direct
// register->global stores. ZERO barriers (qt/wrow already same-wave-only).
__global__ __launch_bounds__(256) void k3_out(const float* __restrict__ x,
        const u16* __restrict__ w_q_bf, const u16* __restrict__ wvln_bf,
        const float* __restrict__ b_qkv, const float* __restrict__ bias2,
        const u16* __restrict__ kvw_t, float* __restrict__ out) {
    __shared__ u16 xw3[4][64 * SW3];   // per-wave x strips bf16: [c][16n]
    __shared__ u16 qt[64 * STK];       // q2: [n][c] bf16 (same-wave rows only)
    __shared__ float wrow_s[4][16];    // per-wave w_row redistribution (same-wave)
    const int tid = threadIdx.x;
    const int w = tid >> 6, lane = tid & 63, q = lane >> 4, l15 = lane & 15;
    const int b = blockIdx.y, g = blockIdx.x;
    const float* xb = x + (size_t)b * 64 * NN;
    // staging: 4 lanes/row, 16 rows/instr; lane covers rows (lane>>2)+16i, floats (lane&3)*4
    const int h16 = lane >> 2, c3 = lane & 3;
    const float* xgw = xb + (size_t)h16 * NN + 16 * w + 4 * c3;
    u16* xs = xw3[w];
    const int sbase = h16 * SW3 + 4 * c3;
    const u16* kvb = kvw_t + (size_t)b * 4096;

    float biasQ[4];
    #pragma unroll
    for (int t4 = 0; t4 < 4; ++t4) biasQ[t4] = b_qkv[16 * t4 + l15];
    float biasO[4][4];   // bias2[d] for d = 16*dt + 4*q + r (d-major accO init)
    #pragma unroll
    for (int dt = 0; dt < 4; ++dt)
        #pragma unroll
        for (int r = 0; r < 4; ++r) biasO[dt][r] = bias2[16 * dt + 4 * q + r];

    // prefetch first tile (4 float4: rows h16+16i of this wave's 16n columns)
    float4 pf[4];
    #pragma unroll
    for (int i = 0; i < 4; ++i)
        pf[i] = *(const float4*)(xgw + (size_t)(16 * i) * NN + (size_t)g * 64);

    for (int t = g; t < NN / 64; t += G3) {
        const int n0 = t * 64;
        // ---- commit prefetched strip to private LDS as bf16 (no barrier)
        #pragma unroll
        for (int i = 0; i < 4; ++i) {
            uint2 pk;
            pk.x = pack2(pf[i].x, pf[i].y);
            pk.y = pack2(pf[i].z, pf[i].w);
            *(uint2*)&xs[sbase + 16 * i * SW3] = pk;
        }
        // ---- issue next tile's loads
        if (t + G3 < NN / 64) {
            #pragma unroll
            for (int i = 0; i < 4; ++i)
                pf[i] = *(const float4*)(xgw + (size_t)(16 * i) * NN + (size_t)(t + G3) * 64);
        }
        // ---- GEMM A: accQ = q (n-major, for stats); accO = o = x@wvln^T + bias2 (d-major)
        f32x4_t accQ[4], accO[4];
        #pragma unroll
        for (int t4 = 0; t4 < 4; ++t4)
            accQ[t4] = (f32x4_t){biasQ[t4], biasQ[t4], biasQ[t4], biasQ[t4]};
        #pragma unroll
        for (int dt = 0; dt < 4; ++dt)
            accO[dt] = (f32x4_t){biasO[dt][0], biasO[dt][1], biasO[dt][2], biasO[dt][3]};
        #pragma unroll
        for (int ks = 0; ks < 2; ++ks) {
            union { u16 u[8]; bf16x8_t v; } af;   // x^T[n][c] frag (same-wave LDS)
            #pragma unroll
            for (int j = 0; j < 8; ++j)
                af.u[j] = xs[(ks * 32 + q * 8 + j) * SW3 + l15];
            #pragma unroll
            for (int t4 = 0; t4 < 4; ++t4) {
                bf16x8_t bq = *(const bf16x8_t*)(w_q_bf + (16 * t4 + l15) * 64 + ks * 32 + q * 8);
                accQ[t4] = __builtin_amdgcn_mfma_f32_16x16x32_bf16(af.v, bq, accQ[t4], 0, 0, 0);
            }
            #pragma unroll
            for (int dt = 0; dt < 4; ++dt) {
                bf16x8_t aw = *(const bf16x8_t*)(wvln_bf + (16 * dt + l15) * 64 + ks * 32 + q * 8);
                accO[dt] = __builtin_amdgcn_mfma_f32_16x16x32_bf16(aw, af.v, accO[dt], 0, 0, 0);
            }
        }
        // ---- q stats via DPP: mu, q2s; q2; w_row = 1/max(||q2||, 1e-12*(q2s+eps))
        float mu[4], q2s[4];
        #pragma unroll
        for (int r = 0; r < 4; ++r) {
            float a0 = accQ[0][r], a1 = accQ[1][r], a2 = accQ[2][r], a3 = accQ[3][r];
            float s1 = row_red16(a0 + a1 + a2 + a3);
            float s2 = row_red16(a0 * a0 + a1 * a1 + a2 * a2 + a3 * a3);
            mu[r] = s1 * 0.015625f;
            q2s[r] = s2 - 64.f * mu[r] * mu[r];
        }
        float q2v[4][4];
        float s4[4] = {0.f, 0.f, 0.f, 0.f};
        #pragma unroll
        for (int t4 = 0; t4 < 4; ++t4)
            #pragma unroll
            for (int r = 0; r < 4; ++r) {
                float d = accQ[t4][r] - mu[r];
                float v2 = d * d;
                q2v[t4][r] = v2;
                s4[r] += v2 * v2;
            }
        float w_row[4];
        #pragma unroll
        for (int r = 0; r < 4; ++r) {
            float s = row_red16(s4[r]);
            w_row[r] = 1.f / fmaxf(sqrtf(s), 1e-12f * (q2s[r] + 1e-7f));
        }
        // ---- redistribute w_row: row n=16w+4q+r -> lane col l15 (same wave only)
        if (l15 == 0) {
            #pragma unroll
            for (int r = 0; r < 4; ++r) wrow_s[w][4 * q + r] = w_row[r];
        }
        // ---- q2 -> qt LDS ([n][c] bf16, same-wave rows)
        #pragma unroll
        for (int t4 = 0; t4 < 4; ++t4)
            #pragma unroll
            for (int r = 0; r < 4; ++r)
                qt[(16 * w + 4 * q + r) * STK + 16 * t4 + l15] = f2bf(q2v[t4][r]);
        // ---- GEMM B (d-major): t2[d][n] = sum_c kvw[d][c]-frag * q2[n][c]
        f32x4_t accB[4];
        #pragma unroll
        for (int dt = 0; dt < 4; ++dt) accB[dt] = (f32x4_t){0.f, 0.f, 0.f, 0.f};
        #pragma unroll
        for (int ks = 0; ks < 2; ++ks) {
            union { bf16x8_t v; uint2 h[2]; } b2;   // q2[n][c] frag as B-operand
            const u16* bp = &qt[(16 * w + l15) * STK + ks * 32 + q * 8];
            b2.h[0] = *(const uint2*)bp;
            b2.h[1] = *(const uint2*)(bp + 4);
            #pragma unroll
            for (int dt = 0; dt < 4; ++dt) {
                bf16x8_t ak = *(const bf16x8_t*)(kvb + (16 * dt + l15) * 64 + ks * 32 + q * 8);
                accB[dt] = __builtin_amdgcn_mfma_f32_16x16x32_bf16(ak, b2.v, accB[dt], 0, 0, 0);
            }
        }
        float wr = wrow_s[w][l15];
        // ---- epilogue: out[d][n] = o + w_row[n]*t2, direct register stores
        #pragma unroll
        for (int dt = 0; dt < 4; ++dt) {
            float* op = out + ((size_t)(b * 64 + 16 * dt + 4 * q)) * NN + n0 + 16 * w + l15;
            #pragma unroll
            for (int r = 0; r < 4; ++r)
                op[(size_t)r * NN] = accO[dt][r] + wr * accB[dt][r];
        }
    }
}

extern "C" void kernel_launch(void* const* d_in, const int* in_sizes, int n_in,
                              void* d_out, int out_size, void* d_ws, size_t ws_size,
                              hipStream_t stream) {
    const float* x     = (const float*)d_in[0];
    const float* w_qkv = (const float*)d_in[1];
    const float* b_qkv = (const float*)d_in[2];
    const float* w_ln  = (const float*)d_in[3];
    const float* b_ln  = (const float*)d_in[4];
    float* out = (float*)d_out;
    char* ws = (char*)d_ws;
    // byte layout (total 12.88 MB, unchanged)
    float* kvu_part = (float*)(ws);                       // 8*96*4096 f32
    float* ksq_part = (float*)(ws + 12582912);            // 8*96*64 f32
    u16*   kvw_t    = (u16*)  (ws + 12779520);            // 8*4096 bf16
    u16*   w_kv_bf  = (u16*)  (ws + 12845056);            // 128*64 bf16
    u16*   w_q_bf   = (u16*)  (ws + 12861440);            // 64*64 bf16
    u16*   wvln_bf  = (u16*)  (ws + 12869632);            // 64*64 bf16
    float* bias2    = (float*)(ws + 12877824);            // 64 f32

    k0_prep<<<dim3(65), dim3(256), 0, stream>>>(w_qkv, b_qkv, w_ln, b_ln,
                                                w_kv_bf, w_q_bf, wvln_bf, bias2);
    k1_kv<<<dim3(G1, 8), dim3(256), 0, stream>>>(x, w_kv_bf, b_qkv, kvu_part, ksq_part);
    k2_kvw<<<dim3(16, 8), dim3(256), 0, stream>>>(kvu_part, ksq_part, w_ln, kvw_t);
    k3_out<<<dim3(G3, 8), dim3(256), 0, stream>>>(x, w_q_bf, wvln_bf, b_qkv, bias2, kvw_t, out);
}